// Round 14
// baseline (282.733 us; speedup 1.0000x reference)
//
#include <hip/hip_runtime.h>
#include <math.h>

#define Nn 8192
#define Dd 256
#define Cc 16

// ---- workspace layout (floats) ----
#define OFF_BP   4194304u    // bf16 packed B fragments (4 MB)
#define OFF_LOG  5242880u    // logits f32 8192*16
#define OFF_G1B  5373952u    // bf16[8192] (gamma-1)
#define OFF_DEN  5378048u    // 4*8192 f32
#define OFF_RS   5410816u    // 4*8192 f32
#define OFF_KC   5443584u    // 64
#define OFF_LB   5443648u    // bf16 packed logits fragments (256 KB)
#define WS_FLOATS 5509184u

typedef short vshort8 __attribute__((ext_vector_type(8)));
typedef float vfloat4 __attribute__((ext_vector_type(4)));

__device__ __forceinline__ float clip1(float x) {
    return fminf(fmaxf(x, -1.0f + 1e-7f), 1.0f - 1e-7f);
}

__device__ __forceinline__ unsigned short f2bf(float f) {
    unsigned int u = __float_as_uint(f);
    u += 0x7fff + ((u >> 16) & 1);          // round-to-nearest-even
    return (unsigned short)(u >> 16);
}

__device__ __forceinline__ float bf2f(unsigned short b) {
    return __uint_as_float(((unsigned int)b) << 16);
}

__device__ __forceinline__ float waveReduce(float v) {
    #pragma unroll
    for (int off = 32; off; off >>= 1) v += __shfl_down(v, off);
    return v;
}

__device__ __forceinline__ float blockReduceBcast(float v, float* red) {
    int t = threadIdx.x, w = t >> 6, l = t & 63;
    v = waveReduce(v);
    if (l == 0) red[w] = v;
    __syncthreads();
    if (t == 0) red[0] = red[0] + red[1] + red[2] + red[3];
    __syncthreads();
    float r = red[0];
    __syncthreads();
    return r;
}

// ---- K0: per-prototype constants ----
__global__ __launch_bounds__(256) void k_consts(const float* __restrict__ Wl,
                                                const float* __restrict__ Pk,
                                                float* __restrict__ kc) {
    __shared__ float red[8];
    int t = threadIdx.x, k = blockIdx.x;
    float pv = Pk[k * Dd + t];
    float wv = Wl[t * Cc + k];
    float p2 = blockReduceBcast(pv * pv, red);
    float pw = blockReduceBcast(pv * wv, red);
    float w2 = blockReduceBcast(wv * wv, red);
    if (t == 0) {
        float an  = fmaxf(sqrtf(w2), 1e-15f);
        float lam = 2.0f / fmaxf(1.0f - p2, 1e-10f);
        kc[k * 4 + 0] = p2; kc[k * 4 + 1] = pw;
        kc[k * 4 + 2] = an; kc[k * 4 + 3] = lam;
    }
}

// ---- K1: fused X@W^T (bf16 MFMA) + mobius rescale + gamma -> packed B ----
__global__ __launch_bounds__(256) void k_front(const float* __restrict__ X,
                                               const float* __restrict__ W,
                                               unsigned short* __restrict__ Bp,
                                               unsigned short* __restrict__ g1b) {
    __shared__ __align__(16) unsigned short Xs[32][256];
    __shared__ __align__(16) unsigned short Gs[32][258];
    __shared__ float xs2[32];
    __shared__ float scal[32];
    __shared__ float red4[32][4];

    const int t = threadIdx.x;
    const int l = t & 63, w = t >> 6;
    const int ll = l & 15, kh = l >> 4;
    const int m0 = blockIdx.x * 32;
    const int ar = t >> 3, aq = t & 7;
    const int c0 = w * 64;

    float x2p = 0.f;
    #pragma unroll
    for (int tc = 0; tc < 4; ++tc) {
        const float* xp = &X[(size_t)(m0 + ar) * Dd + tc * 64 + aq * 8];
        vfloat4 v0 = *(const vfloat4*)xp;
        vfloat4 v1 = *(const vfloat4*)(xp + 4);
        vshort8 o;
        #pragma unroll
        for (int e = 0; e < 4; ++e) {
            x2p += v0[e] * v0[e] + v1[e] * v1[e];
            o[e] = (short)f2bf(v0[e]);
            o[e + 4] = (short)f2bf(v1[e]);
        }
        int byte = (tc * 64 + aq * 8) * 2;
        *(vshort8*)((char*)&Xs[ar][0] + (byte ^ ((ar & 7) << 4))) = o;
    }
    x2p += __shfl_xor(x2p, 1); x2p += __shfl_xor(x2p, 2); x2p += __shfl_xor(x2p, 4);
    if (aq == 0) xs2[ar] = x2p;
    __syncthreads();

    vfloat4 acc[2][4];
    #pragma unroll
    for (int mi = 0; mi < 2; ++mi)
        #pragma unroll
        for (int ni = 0; ni < 4; ++ni)
            acc[mi][ni] = (vfloat4){0.f, 0.f, 0.f, 0.f};
    #pragma unroll
    for (int tc = 0; tc < 4; ++tc) {
        vshort8 bf[8];
        #pragma unroll
        for (int ni = 0; ni < 4; ++ni)
            #pragma unroll
            for (int kk = 0; kk < 2; ++kk) {
                const float* wp = &W[(size_t)(c0 + ni * 16 + ll) * Dd
                                     + tc * 64 + kh * 8 + kk * 32];
                vfloat4 b0 = *(const vfloat4*)wp;
                vfloat4 b1 = *(const vfloat4*)(wp + 4);
                vshort8 o;
                #pragma unroll
                for (int e = 0; e < 4; ++e) {
                    o[e] = (short)f2bf(b0[e]);
                    o[e + 4] = (short)f2bf(b1[e]);
                }
                bf[ni * 2 + kk] = o;
            }
        #pragma unroll
        for (int kk = 0; kk < 2; ++kk) {
            int byte = (tc * 64 + kh * 8 + kk * 32) * 2;
            vshort8 af[2];
            #pragma unroll
            for (int mi = 0; mi < 2; ++mi) {
                int row = mi * 16 + ll;
                af[mi] = *(const vshort8*)((const char*)&Xs[row][0]
                                           + (byte ^ ((row & 7) << 4)));
            }
            #pragma unroll
            for (int mi = 0; mi < 2; ++mi)
                #pragma unroll
                for (int ni = 0; ni < 4; ++ni)
                    acc[mi][ni] = __builtin_amdgcn_mfma_f32_16x16x32_bf16(
                        af[mi], bf[ni * 2 + kk], acc[mi][ni], 0, 0, 0);
        }
    }

    #pragma unroll
    for (int mi = 0; mi < 2; ++mi)
        #pragma unroll
        for (int j = 0; j < 4; ++j) {
            float p = 0.f;
            #pragma unroll
            for (int ni = 0; ni < 4; ++ni)
                p += acc[mi][ni][j] * acc[mi][ni][j];
            p += __shfl_xor(p, 1); p += __shfl_xor(p, 2);
            p += __shfl_xor(p, 4); p += __shfl_xor(p, 8);
            if (ll == 0) red4[mi * 16 + kh * 4 + j][w] = p;
        }
    __syncthreads();

    if (t < 32) {
        float mx2 = red4[t][0] + red4[t][1] + red4[t][2] + red4[t][3];
        float xn = fmaxf(sqrtf(xs2[t]), 1e-15f);
        float mxn = fmaxf(sqrtf(mx2), 1e-15f);
        float s = tanhf(mxn / xn * atanhf(clip1(xn))) / mxn;
        float xw2 = s * s * mx2;
        float gamma = 2.0f / fmaxf(1.0f - xw2, 1e-10f);
        scal[t] = gamma * s;
        g1b[m0 + t] = f2bf(gamma - 1.0f);
    }
    __syncthreads();

    #pragma unroll
    for (int mi = 0; mi < 2; ++mi)
        #pragma unroll
        for (int ni = 0; ni < 4; ++ni) {
            int row = mi * 16 + kh * 4;
            int col = c0 + ni * 16 + ll;
            #pragma unroll
            for (int j = 0; j < 4; ++j)
                Gs[row + j][col] = f2bf(scal[row + j] * acc[mi][ni][j]);
        }
    __syncthreads();

    const int s = blockIdx.x;
    #pragma unroll
    for (int pass = 0; pass < 4; ++pass) {
        int c = pass * 256 + t;
        int gni = c >> 6, lc = c & 63;
        int col = (gni >> 2) * 64 + (gni & 3) * 16 + (lc & 15);
        int kh8 = (lc >> 4) * 8;
        vshort8 o;
        #pragma unroll
        for (int e = 0; e < 8; ++e) o[e] = (short)Gs[kh8 + e][col];
        *(vshort8*)&Bp[((size_t)(s * 16 + gni) * 64 + lc) * 8] = o;
    }
}

// ---- K2: bf16 partials[split] = A(k-slice) @ G -- barrier-free reg MFMA ----
// Wave owns 16 rows x 256 cols (16 acc tiles). Per k-tile: 1 A-frag (2x
// dwordx4, 128B/row contiguous), 16 packed-B frags (coalesced 1KB, L2-local),
// 1 g1 vshort8; 16 MFMA. Double-buffered in regs, distance-1 prefetch.
// No LDS, no barriers; all loads reg-dest -> compiler emits counted vmcnt.
__global__ __launch_bounds__(256, 2) void k_gemm1_mfma(
        const float* __restrict__ A,
        const unsigned short* __restrict__ Bp,
        const unsigned short* __restrict__ g1b,
        unsigned short* __restrict__ Pp,
        float* __restrict__ denp,
        float* __restrict__ rsp) {
    const int t = threadIdx.x, l = t & 63, w = t >> 6;
    const int id = blockIdx.x;
    const int splt = id & 3;                 // XCD (id%8) locked to one split
    const int r0 = (id >> 2) * 64 + w * 16;  // wave's 16 rows
    const int kb = splt * 2048;
    const int kh = l >> 4, ll15 = l & 15;

    const float* Ab = &A[(size_t)(r0 + ll15) * Nn + kb + kh * 8];
    const unsigned short* Bb = Bp + (size_t)(splt * 64) * 8192 + l * 8;
    const unsigned short* g1p = g1b + kb + kh * 8;

    vfloat4 acc[16];
    #pragma unroll
    for (int gni = 0; gni < 16; ++gni)
        acc[gni] = (vfloat4){0.f, 0.f, 0.f, 0.f};
    float dacc = 0.f, racc = 0.f;

    vshort8 bf0[16], bf1[16];
    float a0[8], a1[8];
    vshort8 g10, g11;

    // ---- prologue: tile 0 into buf0 ----
    #pragma unroll
    for (int gni = 0; gni < 16; ++gni)
        bf0[gni] = *(const vshort8*)(Bb + gni * 512);
    {
        const vfloat4* p = (const vfloat4*)(Ab);
        *(vfloat4*)&a0[0] = p[0];
        *(vfloat4*)&a0[4] = p[1];
    }
    g10 = *(const vshort8*)(g1p);

    // ---- 64 k-tiles, unrolled x2 (literal buffer parity) ----
    for (int u = 0; u < 32; ++u) {
        {   // even tile kt = 2u: compute buf0, prefetch kt+1 into buf1
            const int kt = 2 * u;
            #pragma unroll
            for (int gni = 0; gni < 16; ++gni)
                bf1[gni] = *(const vshort8*)(Bb + (kt + 1) * 8192 + gni * 512);
            {
                const vfloat4* p = (const vfloat4*)(Ab + (kt + 1) * 32);
                *(vfloat4*)&a1[0] = p[0];
                *(vfloat4*)&a1[4] = p[1];
            }
            g11 = *(const vshort8*)(g1p + (kt + 1) * 32);
            vshort8 af;
            #pragma unroll
            for (int e = 0; e < 8; ++e) {
                float av = a0[e];
                af[e] = (short)f2bf(av);
                dacc += av * bf2f((unsigned short)g10[e]);
                racc += av;
            }
            #pragma unroll
            for (int gni = 0; gni < 16; ++gni)
                acc[gni] = __builtin_amdgcn_mfma_f32_16x16x32_bf16(
                    af, bf0[gni], acc[gni], 0, 0, 0);
        }
        {   // odd tile kt = 2u+1: compute buf1, prefetch kt+2 into buf0
            const int kt = 2 * u + 1;
            if (kt + 1 < 64) {
                #pragma unroll
                for (int gni = 0; gni < 16; ++gni)
                    bf0[gni] = *(const vshort8*)(Bb + (kt + 1) * 8192 + gni * 512);
                const vfloat4* p = (const vfloat4*)(Ab + (kt + 1) * 32);
                *(vfloat4*)&a0[0] = p[0];
                *(vfloat4*)&a0[4] = p[1];
                g10 = *(const vshort8*)(g1p + (kt + 1) * 32);
            }
            vshort8 af;
            #pragma unroll
            for (int e = 0; e < 8; ++e) {
                float av = a1[e];
                af[e] = (short)f2bf(av);
                dacc += av * bf2f((unsigned short)g11[e]);
                racc += av;
            }
            #pragma unroll
            for (int gni = 0; gni < 16; ++gni)
                acc[gni] = __builtin_amdgcn_mfma_f32_16x16x32_bf16(
                    af, bf1[gni], acc[gni], 0, 0, 0);
        }
    }

    // ---- den/rs: reduce over the 4 kh groups (lanes xor 16/32) ----
    dacc += __shfl_xor(dacc, 16); dacc += __shfl_xor(dacc, 32);
    racc += __shfl_xor(racc, 16); racc += __shfl_xor(racc, 32);
    if (l < 16) {
        denp[splt * Nn + r0 + l] = dacc;
        rsp [splt * Nn + r0 + l] = racc;
    }

    // ---- store bf16 partial ----
    unsigned short* P = Pp + (size_t)splt * ((size_t)Nn * Dd);
    #pragma unroll
    for (int gni = 0; gni < 16; ++gni) {
        int col = (gni >> 2) * 64 + (gni & 3) * 16 + ll15;
        #pragma unroll
        for (int j = 0; j < 4; ++j)
            P[(size_t)(r0 + kh * 4 + j) * Dd + col] = f2bf(acc[gni][j]);
    }
}

// ---- K3: per-row gyromidpoint chain + H1 + hyperbolic logits ----
__global__ __launch_bounds__(256) void k_rowfix(const unsigned short* __restrict__ Pp,
                                                const float* __restrict__ denp,
                                                const float* __restrict__ rsp,
                                                const float* __restrict__ Pk,
                                                const float* __restrict__ Wl,
                                                const float* __restrict__ kc,
                                                float* __restrict__ logits) {
    __shared__ float red[8];
    __shared__ float hs[256];
    __shared__ float PQ[16][2];
    int i = blockIdx.x, t = threadIdx.x;
    float nom = 0.f;
    #pragma unroll
    for (int s = 0; s < 4; ++s)
        nom += bf2f(Pp[(size_t)s * Nn * Dd + (size_t)i * Dd + t]);
    float dv = denp[i] + denp[Nn + i] + denp[2 * Nn + i] + denp[3 * Nn + i];
    dv = (fabsf(dv) < 1e-10f) ? 1e-10f : dv;
    float tm = nom / dv;
    float r2 = blockReduceBcast(tm * tm, red);
    float r = fmaxf(sqrtf(r2), 1e-15f);
    float mmul = tanhf(0.5f * atanhf(clip1(r))) / r;
    float mj = mmul * tm;
    float mn2 = blockReduceBcast(mj * mj, red);
    float mn = fmaxf(sqrtf(mn2), 1e-15f);
    float sA = rsp[i] + rsp[Nn + i] + rsp[2 * Nn + i] + rsp[3 * Nn + i];
    float axmul = tanhf(sA * atanhf(clip1(mn))) / mn;
    float axw = axmul * mj;
    float yn2 = blockReduceBcast(axw * axw, red);
    float yn = fmaxf(sqrtf(yn2), 1e-15f);
    float v = atanhf(clip1(yn)) / yn * axw;
    float u = fmaxf(v, 0.0f);
    float un2 = blockReduceBcast(u * u, red);
    float un = fmaxf(sqrtf(un2), 1e-15f);
    float h = tanhf(un) / un * u;
    float h2 = blockReduceBcast(h * h, red);
    hs[t] = h;
    __syncthreads();
    int w = t >> 6, l = t & 63;
    #pragma unroll
    for (int kk = 0; kk < 4; ++kk) {
        int k = w * 4 + kk;
        float pp = 0.f, qq = 0.f;
        #pragma unroll
        for (int m = 0; m < 4; ++m) {
            float hv = hs[l + 64 * m];
            pp += hv * Pk[k * Dd + l + 64 * m];
            qq += hv * Wl[(l + 64 * m) * Cc + k];
        }
        pp = waveReduce(pp);
        qq = waveReduce(qq);
        if (l == 0) { PQ[k][0] = pp; PQ[k][1] = qq; }
    }
    __syncthreads();
    if (t < 16) {
        int k = t;
        float p2 = kc[k * 4 + 0], pw = kc[k * 4 + 1];
        float an = kc[k * 4 + 2], lam = kc[k * 4 + 3];
        float P = PQ[k][0], Q = PQ[k][1];
        float alpha = 1.0f - 2.0f * P + h2;
        float beta  = 1.0f - p2;
        float Dm = fmaxf(1.0f - 2.0f * P + p2 * h2, 1e-15f);
        float za  = (-alpha * pw + beta * Q) / Dm;
        float zn2 = (alpha * alpha * p2 - 2.0f * alpha * beta * P + beta * beta * h2)
                    / (Dm * Dm);
        float dd = fmaxf(1.0f - zn2, 1e-10f) * an;
        float dist = asinhf(2.0f * za / dd);
        logits[(size_t)i * Cc + k] = lam * an * dist;
    }
}

// ---- K3b: pack logits into MFMA B-fragment layout (bf16) ----
__global__ __launch_bounds__(64) void k_packL(const float* __restrict__ L,
                                              unsigned short* __restrict__ Lb) {
    int kt = blockIdx.x;
    int l = threadIdx.x;
    vshort8 o;
    #pragma unroll
    for (int e = 0; e < 8; ++e)
        o[e] = (short)f2bf(L[(size_t)(kt * 32 + (l >> 4) * 8 + e) * Cc + (l & 15)]);
    *(vshort8*)&Lb[(size_t)kt * 512 + l * 8] = o;
}

// ---- K4: out partials = A @ L via MFMA; no LDS, no barriers ----
__global__ __launch_bounds__(256, 4) void k_gemm2_mfma(
        const float* __restrict__ A,
        const unsigned short* __restrict__ Lb,
        float* __restrict__ part) {
    const int t = threadIdx.x, l = t & 63, w = t >> 6;
    const int id = blockIdx.x;
    const int splt = id & 7;
    const int m0 = (id >> 3) * 64;
    const int kb = splt * 1024;
    const int kh = l >> 4, ll15 = l & 15;
    const int r0 = m0 + w * 16;

    const float* Ab = &A[(size_t)(r0 + ll15) * Nn + kb + kh * 8];
    const unsigned short* Lbb = &Lb[(size_t)(splt * 32) * 512 + l * 8];

    vfloat4 acc = (vfloat4){0.f, 0.f, 0.f, 0.f};
    float a0[8], a1[8], a2[8], a3[8];
    vshort8 b0, b1, b2, b3;

    *(vfloat4*)&a0[0] = *(const vfloat4*)(Ab);
    *(vfloat4*)&a0[4] = *(const vfloat4*)(Ab + 4);
    b0 = *(const vshort8*)(Lbb);
    *(vfloat4*)&a1[0] = *(const vfloat4*)(Ab + 32);
    *(vfloat4*)&a1[4] = *(const vfloat4*)(Ab + 36);
    b1 = *(const vshort8*)(Lbb + 512);
    *(vfloat4*)&a2[0] = *(const vfloat4*)(Ab + 64);
    *(vfloat4*)&a2[4] = *(const vfloat4*)(Ab + 68);
    b2 = *(const vshort8*)(Lbb + 1024);

    for (int u = 0; u < 8; ++u) {
        #pragma unroll
        for (int pp = 0; pp < 4; ++pp) {
            const int kt = u * 4 + pp;
            if (kt < 29) {
                float (&adst)[8] = (pp == 0) ? a3 : (pp == 1) ? a0
                                 : (pp == 2) ? a1 : a2;
                vshort8& bdst = (pp == 0) ? b3 : (pp == 1) ? b0
                              : (pp == 2) ? b1 : b2;
                *(vfloat4*)&adst[0] = *(const vfloat4*)(Ab + (kt + 3) * 32);
                *(vfloat4*)&adst[4] = *(const vfloat4*)(Ab + (kt + 3) * 32 + 4);
                bdst = *(const vshort8*)(Lbb + (kt + 3) * 512);
            }
            float (&acur)[8] = (pp == 0) ? a0 : (pp == 1) ? a1
                             : (pp == 2) ? a2 : a3;
            vshort8& bcur = (pp == 0) ? b0 : (pp == 1) ? b1
                          : (pp == 2) ? b2 : b3;
            vshort8 af;
            #pragma unroll
            for (int e = 0; e < 8; ++e) af[e] = (short)f2bf(acur[e]);
            acc = __builtin_amdgcn_mfma_f32_16x16x32_bf16(af, bcur, acc, 0, 0, 0);
        }
    }

    float* P = part + (size_t)splt * ((size_t)Nn * Cc);
    #pragma unroll
    for (int j = 0; j < 4; ++j)
        P[(size_t)(r0 + kh * 4 + j) * Cc + ll15] = acc[j];
}

// ---- K5: reduce j-split partials (8) ----
__global__ __launch_bounds__(256) void k_reduce(const float* __restrict__ part,
                                                float* __restrict__ out) {
    int i = blockIdx.x * 256 + threadIdx.x;
    float s = 0.f;
    #pragma unroll
    for (int j = 0; j < 8; ++j) s += part[(size_t)j * (Nn * Cc) + i];
    out[i] = s;
}

extern "C" void kernel_launch(void* const* d_in, const int* in_sizes, int n_in,
                              void* d_out, int out_size, void* d_ws, size_t ws_size,
                              hipStream_t stream) {
    const float* X  = (const float*)d_in[0];
    const float* A  = (const float*)d_in[1];
    const float* W  = (const float*)d_in[2];
    const float* Wl = (const float*)d_in[3];
    const float* Pk = (const float*)d_in[4];
    float* out = (float*)d_out;
    float* ws = (float*)d_ws;
    if (ws_size < (size_t)WS_FLOATS * sizeof(float)) return;

    unsigned short* Pp  = (unsigned short*)ws;      // 4 bf16 partials (16MB)
    float* part = ws;                               // gemm2 f32 partials (4MB, later)
    unsigned short* Bp  = (unsigned short*)(ws + OFF_BP);
    float* lg   = ws + OFF_LOG;
    unsigned short* g1b = (unsigned short*)(ws + OFF_G1B);
    float* denp = ws + OFF_DEN;
    float* rsp  = ws + OFF_RS;
    float* kc   = ws + OFF_KC;
    unsigned short* Lbp = (unsigned short*)(ws + OFF_LB);

    k_consts<<<16, 256, 0, stream>>>(Wl, Pk, kc);
    k_front<<<256, 256, 0, stream>>>(X, W, Bp, g1b);
    k_gemm1_mfma<<<512, 256, 0, stream>>>(A, Bp, g1b, Pp, denp, rsp);
    k_rowfix<<<Nn, 256, 0, stream>>>(Pp, denp, rsp, Pk, Wl, kc, lg);
    k_packL<<<256, 64, 0, stream>>>(lg, Lbp);
    k_gemm2_mfma<<<1024, 256, 0, stream>>>(A, Lbp, part);
    k_reduce<<<512, 256, 0, stream>>>(part, out);
}

// Round 15
// 210.212 us; speedup vs baseline: 1.3450x; 1.3450x over previous
//
#include <hip/hip_runtime.h>
#include <math.h>

#define Nn 8192
#define Dd 256
#define Cc 16

// ---- workspace layout (floats) ----
#define OFF_BP   4194304u    // bf16 packed B fragments (4 MB)
#define OFF_LOG  5242880u    // logits f32 8192*16
#define OFF_G1B  5373952u    // bf16[8192] (gamma-1)
#define OFF_DEN  5378048u    // 4*8192 f32
#define OFF_RS   5410816u    // 4*8192 f32
#define OFF_KC   5443584u    // 64
#define OFF_LB   5443648u    // bf16 packed logits fragments (256 KB)
#define WS_FLOATS 5509184u

typedef short vshort8 __attribute__((ext_vector_type(8)));
typedef float vfloat4 __attribute__((ext_vector_type(4)));

#define AS1 __attribute__((address_space(1)))
#define AS3 __attribute__((address_space(3)))

__device__ __forceinline__ float clip1(float x) {
    return fminf(fmaxf(x, -1.0f + 1e-7f), 1.0f - 1e-7f);
}

__device__ __forceinline__ unsigned short f2bf(float f) {
    unsigned int u = __float_as_uint(f);
    u += 0x7fff + ((u >> 16) & 1);          // round-to-nearest-even
    return (unsigned short)(u >> 16);
}

__device__ __forceinline__ float bf2f(unsigned short b) {
    return __uint_as_float(((unsigned int)b) << 16);
}

__device__ __forceinline__ float waveReduce(float v) {
    #pragma unroll
    for (int off = 32; off; off >>= 1) v += __shfl_down(v, off);
    return v;
}

__device__ __forceinline__ float blockReduceBcast(float v, float* red) {
    int t = threadIdx.x, w = t >> 6, l = t & 63;
    v = waveReduce(v);
    if (l == 0) red[w] = v;
    __syncthreads();
    if (t == 0) red[0] = red[0] + red[1] + red[2] + red[3];
    __syncthreads();
    float r = red[0];
    __syncthreads();
    return r;
}

// ---- K0: per-prototype constants ----
__global__ __launch_bounds__(256) void k_consts(const float* __restrict__ Wl,
                                                const float* __restrict__ Pk,
                                                float* __restrict__ kc) {
    __shared__ float red[8];
    int t = threadIdx.x, k = blockIdx.x;
    float pv = Pk[k * Dd + t];
    float wv = Wl[t * Cc + k];
    float p2 = blockReduceBcast(pv * pv, red);
    float pw = blockReduceBcast(pv * wv, red);
    float w2 = blockReduceBcast(wv * wv, red);
    if (t == 0) {
        float an  = fmaxf(sqrtf(w2), 1e-15f);
        float lam = 2.0f / fmaxf(1.0f - p2, 1e-10f);
        kc[k * 4 + 0] = p2; kc[k * 4 + 1] = pw;
        kc[k * 4 + 2] = an; kc[k * 4 + 3] = lam;
    }
}

// ---- K1: fused X@W^T (bf16 MFMA) + mobius rescale + gamma -> packed B ----
__global__ __launch_bounds__(256) void k_front(const float* __restrict__ X,
                                               const float* __restrict__ W,
                                               unsigned short* __restrict__ Bp,
                                               unsigned short* __restrict__ g1b) {
    __shared__ __align__(16) unsigned short Xs[32][256];
    __shared__ __align__(16) unsigned short Gs[32][258];
    __shared__ float xs2[32];
    __shared__ float scal[32];
    __shared__ float red4[32][4];

    const int t = threadIdx.x;
    const int l = t & 63, w = t >> 6;
    const int ll = l & 15, kh = l >> 4;
    const int m0 = blockIdx.x * 32;
    const int ar = t >> 3, aq = t & 7;
    const int c0 = w * 64;

    float x2p = 0.f;
    #pragma unroll
    for (int tc = 0; tc < 4; ++tc) {
        const float* xp = &X[(size_t)(m0 + ar) * Dd + tc * 64 + aq * 8];
        vfloat4 v0 = *(const vfloat4*)xp;
        vfloat4 v1 = *(const vfloat4*)(xp + 4);
        vshort8 o;
        #pragma unroll
        for (int e = 0; e < 4; ++e) {
            x2p += v0[e] * v0[e] + v1[e] * v1[e];
            o[e] = (short)f2bf(v0[e]);
            o[e + 4] = (short)f2bf(v1[e]);
        }
        int byte = (tc * 64 + aq * 8) * 2;
        *(vshort8*)((char*)&Xs[ar][0] + (byte ^ ((ar & 7) << 4))) = o;
    }
    x2p += __shfl_xor(x2p, 1); x2p += __shfl_xor(x2p, 2); x2p += __shfl_xor(x2p, 4);
    if (aq == 0) xs2[ar] = x2p;
    __syncthreads();

    vfloat4 acc[2][4];
    #pragma unroll
    for (int mi = 0; mi < 2; ++mi)
        #pragma unroll
        for (int ni = 0; ni < 4; ++ni)
            acc[mi][ni] = (vfloat4){0.f, 0.f, 0.f, 0.f};
    #pragma unroll
    for (int tc = 0; tc < 4; ++tc) {
        vshort8 bf[8];
        #pragma unroll
        for (int ni = 0; ni < 4; ++ni)
            #pragma unroll
            for (int kk = 0; kk < 2; ++kk) {
                const float* wp = &W[(size_t)(c0 + ni * 16 + ll) * Dd
                                     + tc * 64 + kh * 8 + kk * 32];
                vfloat4 b0 = *(const vfloat4*)wp;
                vfloat4 b1 = *(const vfloat4*)(wp + 4);
                vshort8 o;
                #pragma unroll
                for (int e = 0; e < 4; ++e) {
                    o[e] = (short)f2bf(b0[e]);
                    o[e + 4] = (short)f2bf(b1[e]);
                }
                bf[ni * 2 + kk] = o;
            }
        #pragma unroll
        for (int kk = 0; kk < 2; ++kk) {
            int byte = (tc * 64 + kh * 8 + kk * 32) * 2;
            vshort8 af[2];
            #pragma unroll
            for (int mi = 0; mi < 2; ++mi) {
                int row = mi * 16 + ll;
                af[mi] = *(const vshort8*)((const char*)&Xs[row][0]
                                           + (byte ^ ((row & 7) << 4)));
            }
            #pragma unroll
            for (int mi = 0; mi < 2; ++mi)
                #pragma unroll
                for (int ni = 0; ni < 4; ++ni)
                    acc[mi][ni] = __builtin_amdgcn_mfma_f32_16x16x32_bf16(
                        af[mi], bf[ni * 2 + kk], acc[mi][ni], 0, 0, 0);
        }
    }

    #pragma unroll
    for (int mi = 0; mi < 2; ++mi)
        #pragma unroll
        for (int j = 0; j < 4; ++j) {
            float p = 0.f;
            #pragma unroll
            for (int ni = 0; ni < 4; ++ni)
                p += acc[mi][ni][j] * acc[mi][ni][j];
            p += __shfl_xor(p, 1); p += __shfl_xor(p, 2);
            p += __shfl_xor(p, 4); p += __shfl_xor(p, 8);
            if (ll == 0) red4[mi * 16 + kh * 4 + j][w] = p;
        }
    __syncthreads();

    if (t < 32) {
        float mx2 = red4[t][0] + red4[t][1] + red4[t][2] + red4[t][3];
        float xn = fmaxf(sqrtf(xs2[t]), 1e-15f);
        float mxn = fmaxf(sqrtf(mx2), 1e-15f);
        float s = tanhf(mxn / xn * atanhf(clip1(xn))) / mxn;
        float xw2 = s * s * mx2;
        float gamma = 2.0f / fmaxf(1.0f - xw2, 1e-10f);
        scal[t] = gamma * s;
        g1b[m0 + t] = f2bf(gamma - 1.0f);
    }
    __syncthreads();

    #pragma unroll
    for (int mi = 0; mi < 2; ++mi)
        #pragma unroll
        for (int ni = 0; ni < 4; ++ni) {
            int row = mi * 16 + kh * 4;
            int col = c0 + ni * 16 + ll;
            #pragma unroll
            for (int j = 0; j < 4; ++j)
                Gs[row + j][col] = f2bf(scal[row + j] * acc[mi][ni][j]);
        }
    __syncthreads();

    const int s = blockIdx.x;
    #pragma unroll
    for (int pass = 0; pass < 4; ++pass) {
        int c = pass * 256 + t;
        int gni = c >> 6, lc = c & 63;
        int col = (gni >> 2) * 64 + (gni & 3) * 16 + (lc & 15);
        int kh8 = (lc >> 4) * 8;
        vshort8 o;
        #pragma unroll
        for (int e = 0; e < 8; ++e) o[e] = (short)Gs[kh8 + e][col];
        *(vshort8*)&Bp[((size_t)(s * 16 + gni) * 64 + lc) * 8] = o;
    }
}

// ======== K2 helpers (r10 configuration) ========
__device__ __forceinline__ void g2_issueB(const unsigned short* __restrict__ Bp,
        unsigned short (&BsB)[16][512], int splt, int slab, int w, int l) {
    #pragma unroll
    for (int ni = 0; ni < 4; ++ni)
        __builtin_amdgcn_global_load_lds(
            (const AS1 unsigned int*)
                (Bp + ((size_t)((splt * 64 + slab) * 16 + w * 4 + ni) * 512) + l * 8),
            (AS3 unsigned int*)&BsB[w * 4 + ni][0], 16, 0, 0);
}

__device__ __forceinline__ void g2_loadA(const float* __restrict__ Abase,
                                         int tile, float (&a8)[8]) {
    const vfloat4* p = (const vfloat4*)(Abase + tile * 32);
    *(vfloat4*)&a8[0] = p[0];
    *(vfloat4*)&a8[4] = p[1];
}

__device__ __forceinline__ void g2_stage(unsigned short (&AsB)[2048],
        const unsigned short* g1s, const float (&a8)[8],
        int tile, int rowst, int kq, float& dacc, float& racc) {
    vshort8 gv = *(const vshort8*)&g1s[tile * 32 + kq * 8];
    vshort8 o;
    #pragma unroll
    for (int e = 0; e < 8; ++e) {
        float av = a8[e];
        o[e] = (short)f2bf(av);
        dacc += av * bf2f((unsigned short)gv[e]);
        racc += av;
    }
    *(vshort8*)((char*)&AsB[0] + rowst * 64 + ((kq * 16) ^ ((rowst & 3) << 4))) = o;
}

__device__ __forceinline__ void g2_mfma(const unsigned short (&AsB)[2048],
        const unsigned short (&BsB)[16][512], int w, int kh, int ll15, int l,
        vfloat4 (&acc)[4][4]) {
    vshort8 bf[4], af[4];
    #pragma unroll
    for (int ni = 0; ni < 4; ++ni)
        bf[ni] = *(const vshort8*)&BsB[w * 4 + ni][l * 8];
    #pragma unroll
    for (int mi = 0; mi < 4; ++mi) {
        int row = mi * 16 + ll15;
        af[mi] = *(const vshort8*)((const char*)&AsB[0]
                  + row * 64 + ((kh * 16) ^ ((row & 3) << 4)));
    }
    __builtin_amdgcn_s_setprio(1);
    #pragma unroll
    for (int mi = 0; mi < 4; ++mi)
        #pragma unroll
        for (int ni = 0; ni < 4; ++ni)
            acc[mi][ni] = __builtin_amdgcn_mfma_f32_16x16x32_bf16(
                af[mi], bf[ni], acc[mi][ni], 0, 0, 0);
    __builtin_amdgcn_s_setprio(0);
}

// ---- K2: bf16 partials[split] = A(k-slice) @ G  (r10 best config) ----
__global__ __launch_bounds__(256, 2) void k_gemm1_mfma(
        const float* __restrict__ A,
        const unsigned short* __restrict__ Bp,
        const unsigned short* __restrict__ g1b,
        unsigned short* __restrict__ Pp,
        float* __restrict__ denp,
        float* __restrict__ rsp) {
    __shared__ __align__(16) unsigned short As[2][2048];    // 8 KB
    __shared__ __align__(16) unsigned short Bs[4][16][512]; // 64 KB ring
    __shared__ __align__(16) unsigned short g1s[2048];      // 4 KB

    const int t = threadIdx.x, l = t & 63, w = t >> 6;
    const int id = blockIdx.x;
    const int splt = id & 3;
    const int m0 = (id >> 2) * 64;
    const int kb = splt * 2048;
    const int kh = l >> 4, ll15 = l & 15;
    const int rowst = t >> 2, kq = t & 3;

    const float* Abase = &A[(size_t)(m0 + rowst) * Nn + kb + kq * 8];

    vfloat4 acc[4][4];
    #pragma unroll
    for (int mi = 0; mi < 4; ++mi)
        #pragma unroll
        for (int ni = 0; ni < 4; ++ni)
            acc[mi][ni] = (vfloat4){0.f, 0.f, 0.f, 0.f};
    float dacc = 0.f, racc = 0.f;
    float a0[8], a1[8], a2[8], a3[8];

    uint4 g1v = *(const uint4*)&g1b[kb + t * 8];
    g2_issueB(Bp, Bs[0], splt, 0, w, l);
    g2_issueB(Bp, Bs[1], splt, 1, w, l);
    g2_issueB(Bp, Bs[2], splt, 2, w, l);
    g2_loadA(Abase, 0, a0);
    g2_loadA(Abase, 1, a1);
    g2_loadA(Abase, 2, a2);
    g2_loadA(Abase, 3, a3);
    asm volatile("s_waitcnt vmcnt(0)" ::: "memory");
    *(uint4*)&g1s[t * 8] = g1v;
    asm volatile("s_waitcnt lgkmcnt(0)" ::: "memory");
    __builtin_amdgcn_s_barrier();
    g2_stage(As[0], g1s, a0, 0, rowst, kq, dacc, racc);
    asm volatile("s_waitcnt lgkmcnt(0)" ::: "memory");
    __builtin_amdgcn_s_barrier();
    __builtin_amdgcn_sched_barrier(0);

    for (int u = 0; u < 16; ++u) {
        #pragma unroll
        for (int pp = 0; pp < 4; ++pp) {
            const int q = u * 4 + pp;
            g2_issueB(Bp, Bs[(pp + 3) & 3], splt, (q + 3) & 63, w, l);
            {
                float (&adst)[8] = (pp == 0) ? a0 : (pp == 1) ? a1
                                 : (pp == 2) ? a2 : a3;
                g2_loadA(Abase, (q + 4) & 63, adst);
            }
            asm volatile("s_waitcnt vmcnt(18)" ::: "memory");
            if (q < 63) {
                float (&asrc)[8] = (pp == 0) ? a1 : (pp == 1) ? a2
                                 : (pp == 2) ? a3 : a0;
                g2_stage(As[(q + 1) & 1], g1s, asrc, q + 1, rowst, kq, dacc, racc);
            }
            g2_mfma(As[q & 1], Bs[pp & 3], w, kh, ll15, l, acc);
            asm volatile("s_waitcnt lgkmcnt(0)" ::: "memory");
            __builtin_amdgcn_s_barrier();
            __builtin_amdgcn_sched_barrier(0);
        }
    }

    dacc += __shfl_xor(dacc, 1); dacc += __shfl_xor(dacc, 2);
    racc += __shfl_xor(racc, 1); racc += __shfl_xor(racc, 2);
    if (kq == 0) {
        denp[splt * Nn + m0 + rowst] = dacc;
        rsp [splt * Nn + m0 + rowst] = racc;
    }

    unsigned short* P = Pp + (size_t)splt * ((size_t)Nn * Dd);
    #pragma unroll
    for (int mi = 0; mi < 4; ++mi)
        #pragma unroll
        for (int ni = 0; ni < 4; ++ni) {
            int row = m0 + mi * 16 + (kh << 2);
            int col = w * 64 + ni * 16 + ll15;
            #pragma unroll
            for (int j = 0; j < 4; ++j)
                P[(size_t)(row + j) * Dd + col] = f2bf(acc[mi][ni][j]);
        }
}

// ---- K3: per-row gyromidpoint chain + H1 + hyperbolic logits ----
__global__ __launch_bounds__(256) void k_rowfix(const unsigned short* __restrict__ Pp,
                                                const float* __restrict__ denp,
                                                const float* __restrict__ rsp,
                                                const float* __restrict__ Pk,
                                                const float* __restrict__ Wl,
                                                const float* __restrict__ kc,
                                                float* __restrict__ logits) {
    __shared__ float red[8];
    __shared__ float hs[256];
    __shared__ float PQ[16][2];
    int i = blockIdx.x, t = threadIdx.x;
    float nom = 0.f;
    #pragma unroll
    for (int s = 0; s < 4; ++s)
        nom += bf2f(Pp[(size_t)s * Nn * Dd + (size_t)i * Dd + t]);
    float dv = denp[i] + denp[Nn + i] + denp[2 * Nn + i] + denp[3 * Nn + i];
    dv = (fabsf(dv) < 1e-10f) ? 1e-10f : dv;
    float tm = nom / dv;
    float r2 = blockReduceBcast(tm * tm, red);
    float r = fmaxf(sqrtf(r2), 1e-15f);
    float mmul = tanhf(0.5f * atanhf(clip1(r))) / r;
    float mj = mmul * tm;
    float mn2 = blockReduceBcast(mj * mj, red);
    float mn = fmaxf(sqrtf(mn2), 1e-15f);
    float sA = rsp[i] + rsp[Nn + i] + rsp[2 * Nn + i] + rsp[3 * Nn + i];
    float axmul = tanhf(sA * atanhf(clip1(mn))) / mn;
    float axw = axmul * mj;
    float yn2 = blockReduceBcast(axw * axw, red);
    float yn = fmaxf(sqrtf(yn2), 1e-15f);
    float v = atanhf(clip1(yn)) / yn * axw;
    float u = fmaxf(v, 0.0f);
    float un2 = blockReduceBcast(u * u, red);
    float un = fmaxf(sqrtf(un2), 1e-15f);
    float h = tanhf(un) / un * u;
    float h2 = blockReduceBcast(h * h, red);
    hs[t] = h;
    __syncthreads();
    int w = t >> 6, l = t & 63;
    #pragma unroll
    for (int kk = 0; kk < 4; ++kk) {
        int k = w * 4 + kk;
        float pp = 0.f, qq = 0.f;
        #pragma unroll
        for (int m = 0; m < 4; ++m) {
            float hv = hs[l + 64 * m];
            pp += hv * Pk[k * Dd + l + 64 * m];
            qq += hv * Wl[(l + 64 * m) * Cc + k];
        }
        pp = waveReduce(pp);
        qq = waveReduce(qq);
        if (l == 0) { PQ[k][0] = pp; PQ[k][1] = qq; }
    }
    __syncthreads();
    if (t < 16) {
        int k = t;
        float p2 = kc[k * 4 + 0], pw = kc[k * 4 + 1];
        float an = kc[k * 4 + 2], lam = kc[k * 4 + 3];
        float P = PQ[k][0], Q = PQ[k][1];
        float alpha = 1.0f - 2.0f * P + h2;
        float beta  = 1.0f - p2;
        float Dm = fmaxf(1.0f - 2.0f * P + p2 * h2, 1e-15f);
        float za  = (-alpha * pw + beta * Q) / Dm;
        float zn2 = (alpha * alpha * p2 - 2.0f * alpha * beta * P + beta * beta * h2)
                    / (Dm * Dm);
        float dd = fmaxf(1.0f - zn2, 1e-10f) * an;
        float dist = asinhf(2.0f * za / dd);
        logits[(size_t)i * Cc + k] = lam * an * dist;
    }
}

// ---- K3b: pack logits into MFMA B-fragment layout (bf16) ----
__global__ __launch_bounds__(64) void k_packL(const float* __restrict__ L,
                                              unsigned short* __restrict__ Lb) {
    int kt = blockIdx.x;
    int l = threadIdx.x;
    vshort8 o;
    #pragma unroll
    for (int e = 0; e < 8; ++e)
        o[e] = (short)f2bf(L[(size_t)(kt * 32 + (l >> 4) * 8 + e) * Cc + (l & 15)]);
    *(vshort8*)&Lb[(size_t)kt * 512 + l * 8] = o;
}

// ---- K4: out partials = A @ L via MFMA; no LDS, no barriers ----
__global__ __launch_bounds__(256, 4) void k_gemm2_mfma(
        const float* __restrict__ A,
        const unsigned short* __restrict__ Lb,
        float* __restrict__ part) {
    const int t = threadIdx.x, l = t & 63, w = t >> 6;
    const int id = blockIdx.x;
    const int splt = id & 7;
    const int m0 = (id >> 3) * 64;
    const int kb = splt * 1024;
    const int kh = l >> 4, ll15 = l & 15;
    const int r0 = m0 + w * 16;

    const float* Ab = &A[(size_t)(r0 + ll15) * Nn + kb + kh * 8];
    const unsigned short* Lbb = &Lb[(size_t)(splt * 32) * 512 + l * 8];

    vfloat4 acc = (vfloat4){0.f, 0.f, 0.f, 0.f};
    float a0[8], a1[8], a2[8], a3[8];
    vshort8 b0, b1, b2, b3;

    *(vfloat4*)&a0[0] = *(const vfloat4*)(Ab);
    *(vfloat4*)&a0[4] = *(const vfloat4*)(Ab + 4);
    b0 = *(const vshort8*)(Lbb);
    *(vfloat4*)&a1[0] = *(const vfloat4*)(Ab + 32);
    *(vfloat4*)&a1[4] = *(const vfloat4*)(Ab + 36);
    b1 = *(const vshort8*)(Lbb + 512);
    *(vfloat4*)&a2[0] = *(const vfloat4*)(Ab + 64);
    *(vfloat4*)&a2[4] = *(const vfloat4*)(Ab + 68);
    b2 = *(const vshort8*)(Lbb + 1024);

    for (int u = 0; u < 8; ++u) {
        #pragma unroll
        for (int pp = 0; pp < 4; ++pp) {
            const int kt = u * 4 + pp;
            if (kt < 29) {
                float (&adst)[8] = (pp == 0) ? a3 : (pp == 1) ? a0
                                 : (pp == 2) ? a1 : a2;
                vshort8& bdst = (pp == 0) ? b3 : (pp == 1) ? b0
                              : (pp == 2) ? b1 : b2;
                *(vfloat4*)&adst[0] = *(const vfloat4*)(Ab + (kt + 3) * 32);
                *(vfloat4*)&adst[4] = *(const vfloat4*)(Ab + (kt + 3) * 32 + 4);
                bdst = *(const vshort8*)(Lbb + (kt + 3) * 512);
            }
            float (&acur)[8] = (pp == 0) ? a0 : (pp == 1) ? a1
                             : (pp == 2) ? a2 : a3;
            vshort8& bcur = (pp == 0) ? b0 : (pp == 1) ? b1
                          : (pp == 2) ? b2 : b3;
            vshort8 af;
            #pragma unroll
            for (int e = 0; e < 8; ++e) af[e] = (short)f2bf(acur[e]);
            acc = __builtin_amdgcn_mfma_f32_16x16x32_bf16(af, bcur, acc, 0, 0, 0);
        }
    }

    float* P = part + (size_t)splt * ((size_t)Nn * Cc);
    #pragma unroll
    for (int j = 0; j < 4; ++j)
        P[(size_t)(r0 + kh * 4 + j) * Cc + ll15] = acc[j];
}

// ---- K5: reduce j-split partials (8) ----
__global__ __launch_bounds__(256) void k_reduce(const float* __restrict__ part,
                                                float* __restrict__ out) {
    int i = blockIdx.x * 256 + threadIdx.x;
    float s = 0.f;
    #pragma unroll
    for (int j = 0; j < 8; ++j) s += part[(size_t)j * (Nn * Cc) + i];
    out[i] = s;
}

extern "C" void kernel_launch(void* const* d_in, const int* in_sizes, int n_in,
                              void* d_out, int out_size, void* d_ws, size_t ws_size,
                              hipStream_t stream) {
    const float* X  = (const float*)d_in[0];
    const float* A  = (const float*)d_in[1];
    const float* W  = (const float*)d_in[2];
    const float* Wl = (const float*)d_in[3];
    const float* Pk = (const float*)d_in[4];
    float* out = (float*)d_out;
    float* ws = (float*)d_ws;
    if (ws_size < (size_t)WS_FLOATS * sizeof(float)) return;

    unsigned short* Pp  = (unsigned short*)ws;      // 4 bf16 partials (16MB)
    float* part = ws;                               // gemm2 f32 partials (4MB, later)
    unsigned short* Bp  = (unsigned short*)(ws + OFF_BP);
    float* lg   = ws + OFF_LOG;
    unsigned short* g1b = (unsigned short*)(ws + OFF_G1B);
    float* denp = ws + OFF_DEN;
    float* rsp  = ws + OFF_RS;
    float* kc   = ws + OFF_KC;
    unsigned short* Lbp = (unsigned short*)(ws + OFF_LB);

    k_consts<<<16, 256, 0, stream>>>(Wl, Pk, kc);
    k_front<<<256, 256, 0, stream>>>(X, W, Bp, g1b);
    k_gemm1_mfma<<<512, 256, 0, stream>>>(A, Bp, g1b, Pp, denp, rsp);
    k_rowfix<<<Nn, 256, 0, stream>>>(Pp, denp, rsp, Pk, Wl, kc, lg);
    k_packL<<<256, 64, 0, stream>>>(lg, Lbp);
    k_gemm2_mfma<<<1024, 256, 0, stream>>>(A, Lbp, part);
    k_reduce<<<512, 256, 0, stream>>>(part, out);
}

// Round 16
// 205.056 us; speedup vs baseline: 1.3788x; 1.0251x over previous
//
#include <hip/hip_runtime.h>
#include <math.h>

#define Nn 8192
#define Dd 256
#define Cc 16

// ---- workspace layout (floats) ----
#define OFF_BP   4194304u    // bf16 packed B fragments (4 MB)
#define OFF_G1B  5373952u    // bf16[8192] (gamma-1)
#define OFF_DEN  5378048u    // 4*8192 f32
#define OFF_RS   5410816u    // 4*8192 f32
#define OFF_KC   5443584u    // 64
#define OFF_LB   5443648u    // bf16 packed logits fragments (256 KB)
#define WS_FLOATS 5509184u

typedef short vshort8 __attribute__((ext_vector_type(8)));
typedef float vfloat4 __attribute__((ext_vector_type(4)));

#define AS1 __attribute__((address_space(1)))
#define AS3 __attribute__((address_space(3)))

__device__ __forceinline__ float clip1(float x) {
    return fminf(fmaxf(x, -1.0f + 1e-7f), 1.0f - 1e-7f);
}

__device__ __forceinline__ unsigned short f2bf(float f) {
    unsigned int u = __float_as_uint(f);
    u += 0x7fff + ((u >> 16) & 1);          // round-to-nearest-even
    return (unsigned short)(u >> 16);
}

__device__ __forceinline__ float bf2f(unsigned short b) {
    return __uint_as_float(((unsigned int)b) << 16);
}

__device__ __forceinline__ float waveReduce(float v) {
    #pragma unroll
    for (int off = 32; off; off >>= 1) v += __shfl_down(v, off);
    return v;
}

__device__ __forceinline__ float blockReduceBcast(float v, float* red) {
    int t = threadIdx.x, w = t >> 6, l = t & 63;
    v = waveReduce(v);
    if (l == 0) red[w] = v;
    __syncthreads();
    if (t == 0) red[0] = red[0] + red[1] + red[2] + red[3];
    __syncthreads();
    float r = red[0];
    __syncthreads();
    return r;
}

// ---- K0: per-prototype constants ----
__global__ __launch_bounds__(256) void k_consts(const float* __restrict__ Wl,
                                                const float* __restrict__ Pk,
                                                float* __restrict__ kc) {
    __shared__ float red[8];
    int t = threadIdx.x, k = blockIdx.x;
    float pv = Pk[k * Dd + t];
    float wv = Wl[t * Cc + k];
    float p2 = blockReduceBcast(pv * pv, red);
    float pw = blockReduceBcast(pv * wv, red);
    float w2 = blockReduceBcast(wv * wv, red);
    if (t == 0) {
        float an  = fmaxf(sqrtf(w2), 1e-15f);
        float lam = 2.0f / fmaxf(1.0f - p2, 1e-10f);
        kc[k * 4 + 0] = p2; kc[k * 4 + 1] = pw;
        kc[k * 4 + 2] = an; kc[k * 4 + 3] = lam;
    }
}

// ---- K1: fused X@W^T (bf16 MFMA) + mobius rescale + gamma -> packed B ----
__global__ __launch_bounds__(256) void k_front(const float* __restrict__ X,
                                               const float* __restrict__ W,
                                               unsigned short* __restrict__ Bp,
                                               unsigned short* __restrict__ g1b) {
    __shared__ __align__(16) unsigned short Xs[32][256];
    __shared__ __align__(16) unsigned short Gs[32][258];
    __shared__ float xs2[32];
    __shared__ float scal[32];
    __shared__ float red4[32][4];

    const int t = threadIdx.x;
    const int l = t & 63, w = t >> 6;
    const int ll = l & 15, kh = l >> 4;
    const int m0 = blockIdx.x * 32;
    const int ar = t >> 3, aq = t & 7;
    const int c0 = w * 64;

    float x2p = 0.f;
    #pragma unroll
    for (int tc = 0; tc < 4; ++tc) {
        const float* xp = &X[(size_t)(m0 + ar) * Dd + tc * 64 + aq * 8];
        vfloat4 v0 = *(const vfloat4*)xp;
        vfloat4 v1 = *(const vfloat4*)(xp + 4);
        vshort8 o;
        #pragma unroll
        for (int e = 0; e < 4; ++e) {
            x2p += v0[e] * v0[e] + v1[e] * v1[e];
            o[e] = (short)f2bf(v0[e]);
            o[e + 4] = (short)f2bf(v1[e]);
        }
        int byte = (tc * 64 + aq * 8) * 2;
        *(vshort8*)((char*)&Xs[ar][0] + (byte ^ ((ar & 7) << 4))) = o;
    }
    x2p += __shfl_xor(x2p, 1); x2p += __shfl_xor(x2p, 2); x2p += __shfl_xor(x2p, 4);
    if (aq == 0) xs2[ar] = x2p;
    __syncthreads();

    vfloat4 acc[2][4];
    #pragma unroll
    for (int mi = 0; mi < 2; ++mi)
        #pragma unroll
        for (int ni = 0; ni < 4; ++ni)
            acc[mi][ni] = (vfloat4){0.f, 0.f, 0.f, 0.f};
    #pragma unroll
    for (int tc = 0; tc < 4; ++tc) {
        vshort8 bf[8];
        #pragma unroll
        for (int ni = 0; ni < 4; ++ni)
            #pragma unroll
            for (int kk = 0; kk < 2; ++kk) {
                const float* wp = &W[(size_t)(c0 + ni * 16 + ll) * Dd
                                     + tc * 64 + kh * 8 + kk * 32];
                vfloat4 b0 = *(const vfloat4*)wp;
                vfloat4 b1 = *(const vfloat4*)(wp + 4);
                vshort8 o;
                #pragma unroll
                for (int e = 0; e < 4; ++e) {
                    o[e] = (short)f2bf(b0[e]);
                    o[e + 4] = (short)f2bf(b1[e]);
                }
                bf[ni * 2 + kk] = o;
            }
        #pragma unroll
        for (int kk = 0; kk < 2; ++kk) {
            int byte = (tc * 64 + kh * 8 + kk * 32) * 2;
            vshort8 af[2];
            #pragma unroll
            for (int mi = 0; mi < 2; ++mi) {
                int row = mi * 16 + ll;
                af[mi] = *(const vshort8*)((const char*)&Xs[row][0]
                                           + (byte ^ ((row & 7) << 4)));
            }
            #pragma unroll
            for (int mi = 0; mi < 2; ++mi)
                #pragma unroll
                for (int ni = 0; ni < 4; ++ni)
                    acc[mi][ni] = __builtin_amdgcn_mfma_f32_16x16x32_bf16(
                        af[mi], bf[ni * 2 + kk], acc[mi][ni], 0, 0, 0);
        }
    }

    #pragma unroll
    for (int mi = 0; mi < 2; ++mi)
        #pragma unroll
        for (int j = 0; j < 4; ++j) {
            float p = 0.f;
            #pragma unroll
            for (int ni = 0; ni < 4; ++ni)
                p += acc[mi][ni][j] * acc[mi][ni][j];
            p += __shfl_xor(p, 1); p += __shfl_xor(p, 2);
            p += __shfl_xor(p, 4); p += __shfl_xor(p, 8);
            if (ll == 0) red4[mi * 16 + kh * 4 + j][w] = p;
        }
    __syncthreads();

    if (t < 32) {
        float mx2 = red4[t][0] + red4[t][1] + red4[t][2] + red4[t][3];
        float xn = fmaxf(sqrtf(xs2[t]), 1e-15f);
        float mxn = fmaxf(sqrtf(mx2), 1e-15f);
        float s = tanhf(mxn / xn * atanhf(clip1(xn))) / mxn;
        float xw2 = s * s * mx2;
        float gamma = 2.0f / fmaxf(1.0f - xw2, 1e-10f);
        scal[t] = gamma * s;
        g1b[m0 + t] = f2bf(gamma - 1.0f);
    }
    __syncthreads();

    #pragma unroll
    for (int mi = 0; mi < 2; ++mi)
        #pragma unroll
        for (int ni = 0; ni < 4; ++ni) {
            int row = mi * 16 + kh * 4;
            int col = c0 + ni * 16 + ll;
            #pragma unroll
            for (int j = 0; j < 4; ++j)
                Gs[row + j][col] = f2bf(scal[row + j] * acc[mi][ni][j]);
        }
    __syncthreads();

    const int s = blockIdx.x;
    #pragma unroll
    for (int pass = 0; pass < 4; ++pass) {
        int c = pass * 256 + t;
        int gni = c >> 6, lc = c & 63;
        int col = (gni >> 2) * 64 + (gni & 3) * 16 + (lc & 15);
        int kh8 = (lc >> 4) * 8;
        vshort8 o;
        #pragma unroll
        for (int e = 0; e < 8; ++e) o[e] = (short)Gs[kh8 + e][col];
        *(vshort8*)&Bp[((size_t)(s * 16 + gni) * 64 + lc) * 8] = o;
    }
}

// ======== K2 helpers (r10 configuration) ========
__device__ __forceinline__ void g2_issueB(const unsigned short* __restrict__ Bp,
        unsigned short (&BsB)[16][512], int splt, int slab, int w, int l) {
    #pragma unroll
    for (int ni = 0; ni < 4; ++ni)
        __builtin_amdgcn_global_load_lds(
            (const AS1 unsigned int*)
                (Bp + ((size_t)((splt * 64 + slab) * 16 + w * 4 + ni) * 512) + l * 8),
            (AS3 unsigned int*)&BsB[w * 4 + ni][0], 16, 0, 0);
}

__device__ __forceinline__ void g2_loadA(const float* __restrict__ Abase,
                                         int tile, float (&a8)[8]) {
    const vfloat4* p = (const vfloat4*)(Abase + tile * 32);
    *(vfloat4*)&a8[0] = p[0];
    *(vfloat4*)&a8[4] = p[1];
}

__device__ __forceinline__ void g2_stage(unsigned short (&AsB)[2048],
        const unsigned short* g1s, const float (&a8)[8],
        int tile, int rowst, int kq, float& dacc, float& racc) {
    vshort8 gv = *(const vshort8*)&g1s[tile * 32 + kq * 8];
    vshort8 o;
    #pragma unroll
    for (int e = 0; e < 8; ++e) {
        float av = a8[e];
        o[e] = (short)f2bf(av);
        dacc += av * bf2f((unsigned short)gv[e]);
        racc += av;
    }
    *(vshort8*)((char*)&AsB[0] + rowst * 64 + ((kq * 16) ^ ((rowst & 3) << 4))) = o;
}

__device__ __forceinline__ void g2_mfma(const unsigned short (&AsB)[2048],
        const unsigned short (&BsB)[16][512], int w, int kh, int ll15, int l,
        vfloat4 (&acc)[4][4]) {
    vshort8 bf[4], af[4];
    #pragma unroll
    for (int ni = 0; ni < 4; ++ni)
        bf[ni] = *(const vshort8*)&BsB[w * 4 + ni][l * 8];
    #pragma unroll
    for (int mi = 0; mi < 4; ++mi) {
        int row = mi * 16 + ll15;
        af[mi] = *(const vshort8*)((const char*)&AsB[0]
                  + row * 64 + ((kh * 16) ^ ((row & 3) << 4)));
    }
    __builtin_amdgcn_s_setprio(1);
    #pragma unroll
    for (int mi = 0; mi < 4; ++mi)
        #pragma unroll
        for (int ni = 0; ni < 4; ++ni)
            acc[mi][ni] = __builtin_amdgcn_mfma_f32_16x16x32_bf16(
                af[mi], bf[ni], acc[mi][ni], 0, 0, 0);
    __builtin_amdgcn_s_setprio(0);
}

// ---- K2: bf16 partials[split] = A(k-slice) @ G  (r10 best config) ----
__global__ __launch_bounds__(256, 2) void k_gemm1_mfma(
        const float* __restrict__ A,
        const unsigned short* __restrict__ Bp,
        const unsigned short* __restrict__ g1b,
        unsigned short* __restrict__ Pp,
        float* __restrict__ denp,
        float* __restrict__ rsp) {
    __shared__ __align__(16) unsigned short As[2][2048];    // 8 KB
    __shared__ __align__(16) unsigned short Bs[4][16][512]; // 64 KB ring
    __shared__ __align__(16) unsigned short g1s[2048];      // 4 KB

    const int t = threadIdx.x, l = t & 63, w = t >> 6;
    const int id = blockIdx.x;
    const int splt = id & 3;
    const int m0 = (id >> 2) * 64;
    const int kb = splt * 2048;
    const int kh = l >> 4, ll15 = l & 15;
    const int rowst = t >> 2, kq = t & 3;

    const float* Abase = &A[(size_t)(m0 + rowst) * Nn + kb + kq * 8];

    vfloat4 acc[4][4];
    #pragma unroll
    for (int mi = 0; mi < 4; ++mi)
        #pragma unroll
        for (int ni = 0; ni < 4; ++ni)
            acc[mi][ni] = (vfloat4){0.f, 0.f, 0.f, 0.f};
    float dacc = 0.f, racc = 0.f;
    float a0[8], a1[8], a2[8], a3[8];

    uint4 g1v = *(const uint4*)&g1b[kb + t * 8];
    g2_issueB(Bp, Bs[0], splt, 0, w, l);
    g2_issueB(Bp, Bs[1], splt, 1, w, l);
    g2_issueB(Bp, Bs[2], splt, 2, w, l);
    g2_loadA(Abase, 0, a0);
    g2_loadA(Abase, 1, a1);
    g2_loadA(Abase, 2, a2);
    g2_loadA(Abase, 3, a3);
    asm volatile("s_waitcnt vmcnt(0)" ::: "memory");
    *(uint4*)&g1s[t * 8] = g1v;
    asm volatile("s_waitcnt lgkmcnt(0)" ::: "memory");
    __builtin_amdgcn_s_barrier();
    g2_stage(As[0], g1s, a0, 0, rowst, kq, dacc, racc);
    asm volatile("s_waitcnt lgkmcnt(0)" ::: "memory");
    __builtin_amdgcn_s_barrier();
    __builtin_amdgcn_sched_barrier(0);

    for (int u = 0; u < 16; ++u) {
        #pragma unroll
        for (int pp = 0; pp < 4; ++pp) {
            const int q = u * 4 + pp;
            g2_issueB(Bp, Bs[(pp + 3) & 3], splt, (q + 3) & 63, w, l);
            {
                float (&adst)[8] = (pp == 0) ? a0 : (pp == 1) ? a1
                                 : (pp == 2) ? a2 : a3;
                g2_loadA(Abase, (q + 4) & 63, adst);
            }
            asm volatile("s_waitcnt vmcnt(18)" ::: "memory");
            if (q < 63) {
                float (&asrc)[8] = (pp == 0) ? a1 : (pp == 1) ? a2
                                 : (pp == 2) ? a3 : a0;
                g2_stage(As[(q + 1) & 1], g1s, asrc, q + 1, rowst, kq, dacc, racc);
            }
            g2_mfma(As[q & 1], Bs[pp & 3], w, kh, ll15, l, acc);
            asm volatile("s_waitcnt lgkmcnt(0)" ::: "memory");
            __builtin_amdgcn_s_barrier();
            __builtin_amdgcn_sched_barrier(0);
        }
    }

    dacc += __shfl_xor(dacc, 1); dacc += __shfl_xor(dacc, 2);
    racc += __shfl_xor(racc, 1); racc += __shfl_xor(racc, 2);
    if (kq == 0) {
        denp[splt * Nn + m0 + rowst] = dacc;
        rsp [splt * Nn + m0 + rowst] = racc;
    }

    unsigned short* P = Pp + (size_t)splt * ((size_t)Nn * Dd);
    #pragma unroll
    for (int mi = 0; mi < 4; ++mi)
        #pragma unroll
        for (int ni = 0; ni < 4; ++ni) {
            int row = m0 + mi * 16 + (kh << 2);
            int col = w * 64 + ni * 16 + ll15;
            #pragma unroll
            for (int j = 0; j < 4; ++j)
                P[(size_t)(row + j) * Dd + col] = f2bf(acc[mi][ni][j]);
        }
}

// ---- K3: per-row gyromidpoint chain + H1 + hyperbolic logits ----
// Writes logits DIRECTLY in packed MFMA B-fragment order (fuses old k_packL):
// for row i, col k: Lb[(i>>5)*512 + (((i&31)>>3)*16 + k)*8 + ((i&31)&7)]
__global__ __launch_bounds__(256) void k_rowfix(const unsigned short* __restrict__ Pp,
                                                const float* __restrict__ denp,
                                                const float* __restrict__ rsp,
                                                const float* __restrict__ Pk,
                                                const float* __restrict__ Wl,
                                                const float* __restrict__ kc,
                                                unsigned short* __restrict__ Lb) {
    __shared__ float red[8];
    __shared__ float hs[256];
    __shared__ float PQ[16][2];
    int i = blockIdx.x, t = threadIdx.x;
    float nom = 0.f;
    #pragma unroll
    for (int s = 0; s < 4; ++s)
        nom += bf2f(Pp[(size_t)s * Nn * Dd + (size_t)i * Dd + t]);
    float dv = denp[i] + denp[Nn + i] + denp[2 * Nn + i] + denp[3 * Nn + i];
    dv = (fabsf(dv) < 1e-10f) ? 1e-10f : dv;
    float tm = nom / dv;
    float r2 = blockReduceBcast(tm * tm, red);
    float r = fmaxf(sqrtf(r2), 1e-15f);
    float mmul = tanhf(0.5f * atanhf(clip1(r))) / r;
    float mj = mmul * tm;
    float mn2 = blockReduceBcast(mj * mj, red);
    float mn = fmaxf(sqrtf(mn2), 1e-15f);
    float sA = rsp[i] + rsp[Nn + i] + rsp[2 * Nn + i] + rsp[3 * Nn + i];
    float axmul = tanhf(sA * atanhf(clip1(mn))) / mn;
    float axw = axmul * mj;
    float yn2 = blockReduceBcast(axw * axw, red);
    float yn = fmaxf(sqrtf(yn2), 1e-15f);
    float v = atanhf(clip1(yn)) / yn * axw;
    float u = fmaxf(v, 0.0f);
    float un2 = blockReduceBcast(u * u, red);
    float un = fmaxf(sqrtf(un2), 1e-15f);
    float h = tanhf(un) / un * u;
    float h2 = blockReduceBcast(h * h, red);
    hs[t] = h;
    __syncthreads();
    int w = t >> 6, l = t & 63;
    #pragma unroll
    for (int kk = 0; kk < 4; ++kk) {
        int k = w * 4 + kk;
        float pp = 0.f, qq = 0.f;
        #pragma unroll
        for (int m = 0; m < 4; ++m) {
            float hv = hs[l + 64 * m];
            pp += hv * Pk[k * Dd + l + 64 * m];
            qq += hv * Wl[(l + 64 * m) * Cc + k];
        }
        pp = waveReduce(pp);
        qq = waveReduce(qq);
        if (l == 0) { PQ[k][0] = pp; PQ[k][1] = qq; }
    }
    __syncthreads();
    if (t < 16) {
        int k = t;
        float p2 = kc[k * 4 + 0], pw = kc[k * 4 + 1];
        float an = kc[k * 4 + 2], lam = kc[k * 4 + 3];
        float P = PQ[k][0], Q = PQ[k][1];
        float alpha = 1.0f - 2.0f * P + h2;
        float beta  = 1.0f - p2;
        float Dm = fmaxf(1.0f - 2.0f * P + p2 * h2, 1e-15f);
        float za  = (-alpha * pw + beta * Q) / Dm;
        float zn2 = (alpha * alpha * p2 - 2.0f * alpha * beta * P + beta * beta * h2)
                    / (Dm * Dm);
        float dd = fmaxf(1.0f - zn2, 1e-10f) * an;
        float dist = asinhf(2.0f * za / dd);
        float lgv = lam * an * dist;
        int kt = i >> 5, r = i & 31;
        Lb[(size_t)kt * 512 + (size_t)(((r >> 3) * 16 + k) * 8) + (r & 7)]
            = f2bf(lgv);
    }
}

// ---- K4: out partials = A @ L via MFMA; no LDS, no barriers ----
__global__ __launch_bounds__(256, 4) void k_gemm2_mfma(
        const float* __restrict__ A,
        const unsigned short* __restrict__ Lb,
        float* __restrict__ part) {
    const int t = threadIdx.x, l = t & 63, w = t >> 6;
    const int id = blockIdx.x;
    const int splt = id & 7;
    const int m0 = (id >> 3) * 64;
    const int kb = splt * 1024;
    const int kh = l >> 4, ll15 = l & 15;
    const int r0 = m0 + w * 16;

    const float* Ab = &A[(size_t)(r0 + ll15) * Nn + kb + kh * 8];
    const unsigned short* Lbb = &Lb[(size_t)(splt * 32) * 512 + l * 8];

    vfloat4 acc = (vfloat4){0.f, 0.f, 0.f, 0.f};
    float a0[8], a1[8], a2[8], a3[8];
    vshort8 b0, b1, b2, b3;

    *(vfloat4*)&a0[0] = *(const vfloat4*)(Ab);
    *(vfloat4*)&a0[4] = *(const vfloat4*)(Ab + 4);
    b0 = *(const vshort8*)(Lbb);
    *(vfloat4*)&a1[0] = *(const vfloat4*)(Ab + 32);
    *(vfloat4*)&a1[4] = *(const vfloat4*)(Ab + 36);
    b1 = *(const vshort8*)(Lbb + 512);
    *(vfloat4*)&a2[0] = *(const vfloat4*)(Ab + 64);
    *(vfloat4*)&a2[4] = *(const vfloat4*)(Ab + 68);
    b2 = *(const vshort8*)(Lbb + 1024);

    for (int u = 0; u < 8; ++u) {
        #pragma unroll
        for (int pp = 0; pp < 4; ++pp) {
            const int kt = u * 4 + pp;
            if (kt < 29) {
                float (&adst)[8] = (pp == 0) ? a3 : (pp == 1) ? a0
                                 : (pp == 2) ? a1 : a2;
                vshort8& bdst = (pp == 0) ? b3 : (pp == 1) ? b0
                              : (pp == 2) ? b1 : b2;
                *(vfloat4*)&adst[0] = *(const vfloat4*)(Ab + (kt + 3) * 32);
                *(vfloat4*)&adst[4] = *(const vfloat4*)(Ab + (kt + 3) * 32 + 4);
                bdst = *(const vshort8*)(Lbb + (kt + 3) * 512);
            }
            float (&acur)[8] = (pp == 0) ? a0 : (pp == 1) ? a1
                             : (pp == 2) ? a2 : a3;
            vshort8& bcur = (pp == 0) ? b0 : (pp == 1) ? b1
                          : (pp == 2) ? b2 : b3;
            vshort8 af;
            #pragma unroll
            for (int e = 0; e < 8; ++e) af[e] = (short)f2bf(acur[e]);
            acc = __builtin_amdgcn_mfma_f32_16x16x32_bf16(af, bcur, acc, 0, 0, 0);
        }
    }

    float* P = part + (size_t)splt * ((size_t)Nn * Cc);
    #pragma unroll
    for (int j = 0; j < 4; ++j)
        P[(size_t)(r0 + kh * 4 + j) * Cc + ll15] = acc[j];
}

// ---- K5: reduce j-split partials (8) ----
__global__ __launch_bounds__(256) void k_reduce(const float* __restrict__ part,
                                                float* __restrict__ out) {
    int i = blockIdx.x * 256 + threadIdx.x;
    float s = 0.f;
    #pragma unroll
    for (int j = 0; j < 8; ++j) s += part[(size_t)j * (Nn * Cc) + i];
    out[i] = s;
}

extern "C" void kernel_launch(void* const* d_in, const int* in_sizes, int n_in,
                              void* d_out, int out_size, void* d_ws, size_t ws_size,
                              hipStream_t stream) {
    const float* X  = (const float*)d_in[0];
    const float* A  = (const float*)d_in[1];
    const float* W  = (const float*)d_in[2];
    const float* Wl = (const float*)d_in[3];
    const float* Pk = (const float*)d_in[4];
    float* out = (float*)d_out;
    float* ws = (float*)d_ws;
    if (ws_size < (size_t)WS_FLOATS * sizeof(float)) return;

    unsigned short* Pp  = (unsigned short*)ws;      // 4 bf16 partials (16MB)
    float* part = ws;                               // gemm2 f32 partials (4MB, later)
    unsigned short* Bp  = (unsigned short*)(ws + OFF_BP);
    unsigned short* g1b = (unsigned short*)(ws + OFF_G1B);
    float* denp = ws + OFF_DEN;
    float* rsp  = ws + OFF_RS;
    float* kc   = ws + OFF_KC;
    unsigned short* Lbp = (unsigned short*)(ws + OFF_LB);

    k_consts<<<16, 256, 0, stream>>>(Wl, Pk, kc);
    k_front<<<256, 256, 0, stream>>>(X, W, Bp, g1b);
    k_gemm1_mfma<<<512, 256, 0, stream>>>(A, Bp, g1b, Pp, denp, rsp);
    k_rowfix<<<Nn, 256, 0, stream>>>(Pp, denp, rsp, Pk, Wl, kc, Lbp);
    k_gemm2_mfma<<<1024, 256, 0, stream>>>(A, Lbp, part);
    k_reduce<<<512, 256, 0, stream>>>(part, out);
}

// Round 17
// 204.340 us; speedup vs baseline: 1.3836x; 1.0035x over previous
//
#include <hip/hip_runtime.h>
#include <math.h>

#define Nn 8192
#define Dd 256
#define Cc 16

// ---- workspace layout (floats) ----
#define OFF_BP   4194304u    // bf16 packed B fragments (4 MB)
#define OFF_G1B  5373952u    // bf16[8192] (gamma-1)
#define OFF_DEN  5378048u    // 4*8192 f32
#define OFF_RS   5410816u    // 4*8192 f32
#define OFF_KC   5443584u    // 64
#define OFF_LB   5443648u    // bf16 packed logits fragments (256 KB)
#define WS_FLOATS 5509184u

typedef short vshort8 __attribute__((ext_vector_type(8)));
typedef float vfloat4 __attribute__((ext_vector_type(4)));

#define AS1 __attribute__((address_space(1)))
#define AS3 __attribute__((address_space(3)))

__device__ __forceinline__ float clip1(float x) {
    return fminf(fmaxf(x, -1.0f + 1e-7f), 1.0f - 1e-7f);
}

__device__ __forceinline__ unsigned short f2bf(float f) {
    unsigned int u = __float_as_uint(f);
    u += 0x7fff + ((u >> 16) & 1);          // round-to-nearest-even
    return (unsigned short)(u >> 16);
}

__device__ __forceinline__ float bf2f(unsigned short b) {
    return __uint_as_float(((unsigned int)b) << 16);
}

__device__ __forceinline__ float waveReduce(float v) {
    #pragma unroll
    for (int off = 32; off; off >>= 1) v += __shfl_down(v, off);
    return v;
}

__device__ __forceinline__ float blockReduceBcast(float v, float* red) {
    int t = threadIdx.x, w = t >> 6, l = t & 63;
    v = waveReduce(v);
    if (l == 0) red[w] = v;
    __syncthreads();
    if (t == 0) red[0] = red[0] + red[1] + red[2] + red[3];
    __syncthreads();
    float r = red[0];
    __syncthreads();
    return r;
}

// ---- K1: fused X@W^T (bf16 MFMA) + mobius rescale + gamma -> packed B ----
// Blocks 0..255: main front work. Blocks 256..271: per-prototype constants
// (folded former k_consts; saves one launch + gap).
__global__ __launch_bounds__(256) void k_front(const float* __restrict__ X,
                                               const float* __restrict__ W,
                                               const float* __restrict__ Wl,
                                               const float* __restrict__ Pk,
                                               unsigned short* __restrict__ Bp,
                                               unsigned short* __restrict__ g1b,
                                               float* __restrict__ kc) {
    __shared__ __align__(16) unsigned short Xs[32][256];
    __shared__ __align__(16) unsigned short Gs[32][258];
    __shared__ float xs2[32];
    __shared__ float scal[32];
    __shared__ float red4[32][4];

    const int t = threadIdx.x;

    if (blockIdx.x >= 256) {                 // ---- consts role ----
        int k = blockIdx.x - 256;
        float* red = &red4[0][0];
        float pv = Pk[k * Dd + t];
        float wv = Wl[t * Cc + k];
        float p2 = blockReduceBcast(pv * pv, red);
        float pw = blockReduceBcast(pv * wv, red);
        float w2 = blockReduceBcast(wv * wv, red);
        if (t == 0) {
            float an  = fmaxf(sqrtf(w2), 1e-15f);
            float lam = 2.0f / fmaxf(1.0f - p2, 1e-10f);
            kc[k * 4 + 0] = p2; kc[k * 4 + 1] = pw;
            kc[k * 4 + 2] = an; kc[k * 4 + 3] = lam;
        }
        return;
    }

    const int l = t & 63, w = t >> 6;
    const int ll = l & 15, kh = l >> 4;
    const int m0 = blockIdx.x * 32;
    const int ar = t >> 3, aq = t & 7;
    const int c0 = w * 64;

    float x2p = 0.f;
    #pragma unroll
    for (int tc = 0; tc < 4; ++tc) {
        const float* xp = &X[(size_t)(m0 + ar) * Dd + tc * 64 + aq * 8];
        vfloat4 v0 = *(const vfloat4*)xp;
        vfloat4 v1 = *(const vfloat4*)(xp + 4);
        vshort8 o;
        #pragma unroll
        for (int e = 0; e < 4; ++e) {
            x2p += v0[e] * v0[e] + v1[e] * v1[e];
            o[e] = (short)f2bf(v0[e]);
            o[e + 4] = (short)f2bf(v1[e]);
        }
        int byte = (tc * 64 + aq * 8) * 2;
        *(vshort8*)((char*)&Xs[ar][0] + (byte ^ ((ar & 7) << 4))) = o;
    }
    x2p += __shfl_xor(x2p, 1); x2p += __shfl_xor(x2p, 2); x2p += __shfl_xor(x2p, 4);
    if (aq == 0) xs2[ar] = x2p;
    __syncthreads();

    vfloat4 acc[2][4];
    #pragma unroll
    for (int mi = 0; mi < 2; ++mi)
        #pragma unroll
        for (int ni = 0; ni < 4; ++ni)
            acc[mi][ni] = (vfloat4){0.f, 0.f, 0.f, 0.f};
    #pragma unroll
    for (int tc = 0; tc < 4; ++tc) {
        vshort8 bf[8];
        #pragma unroll
        for (int ni = 0; ni < 4; ++ni)
            #pragma unroll
            for (int kk = 0; kk < 2; ++kk) {
                const float* wp = &W[(size_t)(c0 + ni * 16 + ll) * Dd
                                     + tc * 64 + kh * 8 + kk * 32];
                vfloat4 b0 = *(const vfloat4*)wp;
                vfloat4 b1 = *(const vfloat4*)(wp + 4);
                vshort8 o;
                #pragma unroll
                for (int e = 0; e < 4; ++e) {
                    o[e] = (short)f2bf(b0[e]);
                    o[e + 4] = (short)f2bf(b1[e]);
                }
                bf[ni * 2 + kk] = o;
            }
        #pragma unroll
        for (int kk = 0; kk < 2; ++kk) {
            int byte = (tc * 64 + kh * 8 + kk * 32) * 2;
            vshort8 af[2];
            #pragma unroll
            for (int mi = 0; mi < 2; ++mi) {
                int row = mi * 16 + ll;
                af[mi] = *(const vshort8*)((const char*)&Xs[row][0]
                                           + (byte ^ ((row & 7) << 4)));
            }
            #pragma unroll
            for (int mi = 0; mi < 2; ++mi)
                #pragma unroll
                for (int ni = 0; ni < 4; ++ni)
                    acc[mi][ni] = __builtin_amdgcn_mfma_f32_16x16x32_bf16(
                        af[mi], bf[ni * 2 + kk], acc[mi][ni], 0, 0, 0);
        }
    }

    #pragma unroll
    for (int mi = 0; mi < 2; ++mi)
        #pragma unroll
        for (int j = 0; j < 4; ++j) {
            float p = 0.f;
            #pragma unroll
            for (int ni = 0; ni < 4; ++ni)
                p += acc[mi][ni][j] * acc[mi][ni][j];
            p += __shfl_xor(p, 1); p += __shfl_xor(p, 2);
            p += __shfl_xor(p, 4); p += __shfl_xor(p, 8);
            if (ll == 0) red4[mi * 16 + kh * 4 + j][w] = p;
        }
    __syncthreads();

    if (t < 32) {
        float mx2 = red4[t][0] + red4[t][1] + red4[t][2] + red4[t][3];
        float xn = fmaxf(sqrtf(xs2[t]), 1e-15f);
        float mxn = fmaxf(sqrtf(mx2), 1e-15f);
        float s = tanhf(mxn / xn * atanhf(clip1(xn))) / mxn;
        float xw2 = s * s * mx2;
        float gamma = 2.0f / fmaxf(1.0f - xw2, 1e-10f);
        scal[t] = gamma * s;
        g1b[m0 + t] = f2bf(gamma - 1.0f);
    }
    __syncthreads();

    #pragma unroll
    for (int mi = 0; mi < 2; ++mi)
        #pragma unroll
        for (int ni = 0; ni < 4; ++ni) {
            int row = mi * 16 + kh * 4;
            int col = c0 + ni * 16 + ll;
            #pragma unroll
            for (int j = 0; j < 4; ++j)
                Gs[row + j][col] = f2bf(scal[row + j] * acc[mi][ni][j]);
        }
    __syncthreads();

    const int s = blockIdx.x;
    #pragma unroll
    for (int pass = 0; pass < 4; ++pass) {
        int c = pass * 256 + t;
        int gni = c >> 6, lc = c & 63;
        int col = (gni >> 2) * 64 + (gni & 3) * 16 + (lc & 15);
        int kh8 = (lc >> 4) * 8;
        vshort8 o;
        #pragma unroll
        for (int e = 0; e < 8; ++e) o[e] = (short)Gs[kh8 + e][col];
        *(vshort8*)&Bp[((size_t)(s * 16 + gni) * 64 + lc) * 8] = o;
    }
}

// ======== K2 helpers (r10 configuration) ========
__device__ __forceinline__ void g2_issueB(const unsigned short* __restrict__ Bp,
        unsigned short (&BsB)[16][512], int splt, int slab, int w, int l) {
    #pragma unroll
    for (int ni = 0; ni < 4; ++ni)
        __builtin_amdgcn_global_load_lds(
            (const AS1 unsigned int*)
                (Bp + ((size_t)((splt * 64 + slab) * 16 + w * 4 + ni) * 512) + l * 8),
            (AS3 unsigned int*)&BsB[w * 4 + ni][0], 16, 0, 0);
}

__device__ __forceinline__ void g2_loadA(const float* __restrict__ Abase,
                                         int tile, float (&a8)[8]) {
    const vfloat4* p = (const vfloat4*)(Abase + tile * 32);
    *(vfloat4*)&a8[0] = p[0];
    *(vfloat4*)&a8[4] = p[1];
}

__device__ __forceinline__ void g2_stage(unsigned short (&AsB)[2048],
        const unsigned short* g1s, const float (&a8)[8],
        int tile, int rowst, int kq, float& dacc, float& racc) {
    vshort8 gv = *(const vshort8*)&g1s[tile * 32 + kq * 8];
    vshort8 o;
    #pragma unroll
    for (int e = 0; e < 8; ++e) {
        float av = a8[e];
        o[e] = (short)f2bf(av);
        dacc += av * bf2f((unsigned short)gv[e]);
        racc += av;
    }
    *(vshort8*)((char*)&AsB[0] + rowst * 64 + ((kq * 16) ^ ((rowst & 3) << 4))) = o;
}

__device__ __forceinline__ void g2_mfma(const unsigned short (&AsB)[2048],
        const unsigned short (&BsB)[16][512], int w, int kh, int ll15, int l,
        vfloat4 (&acc)[4][4]) {
    vshort8 bf[4], af[4];
    #pragma unroll
    for (int ni = 0; ni < 4; ++ni)
        bf[ni] = *(const vshort8*)&BsB[w * 4 + ni][l * 8];
    #pragma unroll
    for (int mi = 0; mi < 4; ++mi) {
        int row = mi * 16 + ll15;
        af[mi] = *(const vshort8*)((const char*)&AsB[0]
                  + row * 64 + ((kh * 16) ^ ((row & 3) << 4)));
    }
    __builtin_amdgcn_s_setprio(1);
    #pragma unroll
    for (int mi = 0; mi < 4; ++mi)
        #pragma unroll
        for (int ni = 0; ni < 4; ++ni)
            acc[mi][ni] = __builtin_amdgcn_mfma_f32_16x16x32_bf16(
                af[mi], bf[ni], acc[mi][ni], 0, 0, 0);
    __builtin_amdgcn_s_setprio(0);
}

// ---- K2: bf16 partials[split] = A(k-slice) @ G  (r10 best config) ----
__global__ __launch_bounds__(256, 2) void k_gemm1_mfma(
        const float* __restrict__ A,
        const unsigned short* __restrict__ Bp,
        const unsigned short* __restrict__ g1b,
        unsigned short* __restrict__ Pp,
        float* __restrict__ denp,
        float* __restrict__ rsp) {
    __shared__ __align__(16) unsigned short As[2][2048];    // 8 KB
    __shared__ __align__(16) unsigned short Bs[4][16][512]; // 64 KB ring
    __shared__ __align__(16) unsigned short g1s[2048];      // 4 KB

    const int t = threadIdx.x, l = t & 63, w = t >> 6;
    const int id = blockIdx.x;
    const int splt = id & 3;
    const int m0 = (id >> 2) * 64;
    const int kb = splt * 2048;
    const int kh = l >> 4, ll15 = l & 15;
    const int rowst = t >> 2, kq = t & 3;

    const float* Abase = &A[(size_t)(m0 + rowst) * Nn + kb + kq * 8];

    vfloat4 acc[4][4];
    #pragma unroll
    for (int mi = 0; mi < 4; ++mi)
        #pragma unroll
        for (int ni = 0; ni < 4; ++ni)
            acc[mi][ni] = (vfloat4){0.f, 0.f, 0.f, 0.f};
    float dacc = 0.f, racc = 0.f;
    float a0[8], a1[8], a2[8], a3[8];

    uint4 g1v = *(const uint4*)&g1b[kb + t * 8];
    g2_issueB(Bp, Bs[0], splt, 0, w, l);
    g2_issueB(Bp, Bs[1], splt, 1, w, l);
    g2_issueB(Bp, Bs[2], splt, 2, w, l);
    g2_loadA(Abase, 0, a0);
    g2_loadA(Abase, 1, a1);
    g2_loadA(Abase, 2, a2);
    g2_loadA(Abase, 3, a3);
    asm volatile("s_waitcnt vmcnt(0)" ::: "memory");
    *(uint4*)&g1s[t * 8] = g1v;
    asm volatile("s_waitcnt lgkmcnt(0)" ::: "memory");
    __builtin_amdgcn_s_barrier();
    g2_stage(As[0], g1s, a0, 0, rowst, kq, dacc, racc);
    asm volatile("s_waitcnt lgkmcnt(0)" ::: "memory");
    __builtin_amdgcn_s_barrier();
    __builtin_amdgcn_sched_barrier(0);

    for (int u = 0; u < 16; ++u) {
        #pragma unroll
        for (int pp = 0; pp < 4; ++pp) {
            const int q = u * 4 + pp;
            g2_issueB(Bp, Bs[(pp + 3) & 3], splt, (q + 3) & 63, w, l);
            {
                float (&adst)[8] = (pp == 0) ? a0 : (pp == 1) ? a1
                                 : (pp == 2) ? a2 : a3;
                g2_loadA(Abase, (q + 4) & 63, adst);
            }
            asm volatile("s_waitcnt vmcnt(18)" ::: "memory");
            if (q < 63) {
                float (&asrc)[8] = (pp == 0) ? a1 : (pp == 1) ? a2
                                 : (pp == 2) ? a3 : a0;
                g2_stage(As[(q + 1) & 1], g1s, asrc, q + 1, rowst, kq, dacc, racc);
            }
            g2_mfma(As[q & 1], Bs[pp & 3], w, kh, ll15, l, acc);
            asm volatile("s_waitcnt lgkmcnt(0)" ::: "memory");
            __builtin_amdgcn_s_barrier();
            __builtin_amdgcn_sched_barrier(0);
        }
    }

    dacc += __shfl_xor(dacc, 1); dacc += __shfl_xor(dacc, 2);
    racc += __shfl_xor(racc, 1); racc += __shfl_xor(racc, 2);
    if (kq == 0) {
        denp[splt * Nn + m0 + rowst] = dacc;
        rsp [splt * Nn + m0 + rowst] = racc;
    }

    unsigned short* P = Pp + (size_t)splt * ((size_t)Nn * Dd);
    #pragma unroll
    for (int mi = 0; mi < 4; ++mi)
        #pragma unroll
        for (int ni = 0; ni < 4; ++ni) {
            int row = m0 + mi * 16 + (kh << 2);
            int col = w * 64 + ni * 16 + ll15;
            #pragma unroll
            for (int j = 0; j < 4; ++j)
                P[(size_t)(row + j) * Dd + col] = f2bf(acc[mi][ni][j]);
        }
}

// ---- K3: per-row gyromidpoint chain + H1 + hyperbolic logits ----
// Writes logits DIRECTLY in packed MFMA B-fragment order.
__global__ __launch_bounds__(256) void k_rowfix(const unsigned short* __restrict__ Pp,
                                                const float* __restrict__ denp,
                                                const float* __restrict__ rsp,
                                                const float* __restrict__ Pk,
                                                const float* __restrict__ Wl,
                                                const float* __restrict__ kc,
                                                unsigned short* __restrict__ Lb) {
    __shared__ float red[8];
    __shared__ float hs[256];
    __shared__ float PQ[16][2];
    int i = blockIdx.x, t = threadIdx.x;
    float nom = 0.f;
    #pragma unroll
    for (int s = 0; s < 4; ++s)
        nom += bf2f(Pp[(size_t)s * Nn * Dd + (size_t)i * Dd + t]);
    float dv = denp[i] + denp[Nn + i] + denp[2 * Nn + i] + denp[3 * Nn + i];
    dv = (fabsf(dv) < 1e-10f) ? 1e-10f : dv;
    float tm = nom / dv;
    float r2 = blockReduceBcast(tm * tm, red);
    float r = fmaxf(sqrtf(r2), 1e-15f);
    float mmul = tanhf(0.5f * atanhf(clip1(r))) / r;
    float mj = mmul * tm;
    float mn2 = blockReduceBcast(mj * mj, red);
    float mn = fmaxf(sqrtf(mn2), 1e-15f);
    float sA = rsp[i] + rsp[Nn + i] + rsp[2 * Nn + i] + rsp[3 * Nn + i];
    float axmul = tanhf(sA * atanhf(clip1(mn))) / mn;
    float axw = axmul * mj;
    float yn2 = blockReduceBcast(axw * axw, red);
    float yn = fmaxf(sqrtf(yn2), 1e-15f);
    float v = atanhf(clip1(yn)) / yn * axw;
    float u = fmaxf(v, 0.0f);
    float un2 = blockReduceBcast(u * u, red);
    float un = fmaxf(sqrtf(un2), 1e-15f);
    float h = tanhf(un) / un * u;
    float h2 = blockReduceBcast(h * h, red);
    hs[t] = h;
    __syncthreads();
    int w = t >> 6, l = t & 63;
    #pragma unroll
    for (int kk = 0; kk < 4; ++kk) {
        int k = w * 4 + kk;
        float pp = 0.f, qq = 0.f;
        #pragma unroll
        for (int m = 0; m < 4; ++m) {
            float hv = hs[l + 64 * m];
            pp += hv * Pk[k * Dd + l + 64 * m];
            qq += hv * Wl[(l + 64 * m) * Cc + k];
        }
        pp = waveReduce(pp);
        qq = waveReduce(qq);
        if (l == 0) { PQ[k][0] = pp; PQ[k][1] = qq; }
    }
    __syncthreads();
    if (t < 16) {
        int k = t;
        float p2 = kc[k * 4 + 0], pw = kc[k * 4 + 1];
        float an = kc[k * 4 + 2], lam = kc[k * 4 + 3];
        float P = PQ[k][0], Q = PQ[k][1];
        float alpha = 1.0f - 2.0f * P + h2;
        float beta  = 1.0f - p2;
        float Dm = fmaxf(1.0f - 2.0f * P + p2 * h2, 1e-15f);
        float za  = (-alpha * pw + beta * Q) / Dm;
        float zn2 = (alpha * alpha * p2 - 2.0f * alpha * beta * P + beta * beta * h2)
                    / (Dm * Dm);
        float dd = fmaxf(1.0f - zn2, 1e-10f) * an;
        float dist = asinhf(2.0f * za / dd);
        float lgv = lam * an * dist;
        int kt = i >> 5, r = i & 31;
        Lb[(size_t)kt * 512 + (size_t)(((r >> 3) * 16 + k) * 8) + (r & 7)]
            = f2bf(lgv);
    }
}

// ---- K4: out partials = A @ L via MFMA; no LDS, no barriers ----
__global__ __launch_bounds__(256, 4) void k_gemm2_mfma(
        const float* __restrict__ A,
        const unsigned short* __restrict__ Lb,
        float* __restrict__ part) {
    const int t = threadIdx.x, l = t & 63, w = t >> 6;
    const int id = blockIdx.x;
    const int splt = id & 7;
    const int m0 = (id >> 3) * 64;
    const int kb = splt * 1024;
    const int kh = l >> 4, ll15 = l & 15;
    const int r0 = m0 + w * 16;

    const float* Ab = &A[(size_t)(r0 + ll15) * Nn + kb + kh * 8];
    const unsigned short* Lbb = &Lb[(size_t)(splt * 32) * 512 + l * 8];

    vfloat4 acc = (vfloat4){0.f, 0.f, 0.f, 0.f};
    float a0[8], a1[8], a2[8], a3[8];
    vshort8 b0, b1, b2, b3;

    *(vfloat4*)&a0[0] = *(const vfloat4*)(Ab);
    *(vfloat4*)&a0[4] = *(const vfloat4*)(Ab + 4);
    b0 = *(const vshort8*)(Lbb);
    *(vfloat4*)&a1[0] = *(const vfloat4*)(Ab + 32);
    *(vfloat4*)&a1[4] = *(const vfloat4*)(Ab + 36);
    b1 = *(const vshort8*)(Lbb + 512);
    *(vfloat4*)&a2[0] = *(const vfloat4*)(Ab + 64);
    *(vfloat4*)&a2[4] = *(const vfloat4*)(Ab + 68);
    b2 = *(const vshort8*)(Lbb + 1024);

    for (int u = 0; u < 8; ++u) {
        #pragma unroll
        for (int pp = 0; pp < 4; ++pp) {
            const int kt = u * 4 + pp;
            if (kt < 29) {
                float (&adst)[8] = (pp == 0) ? a3 : (pp == 1) ? a0
                                 : (pp == 2) ? a1 : a2;
                vshort8& bdst = (pp == 0) ? b3 : (pp == 1) ? b0
                              : (pp == 2) ? b1 : b2;
                *(vfloat4*)&adst[0] = *(const vfloat4*)(Ab + (kt + 3) * 32);
                *(vfloat4*)&adst[4] = *(const vfloat4*)(Ab + (kt + 3) * 32 + 4);
                bdst = *(const vshort8*)(Lbb + (kt + 3) * 512);
            }
            float (&acur)[8] = (pp == 0) ? a0 : (pp == 1) ? a1
                             : (pp == 2) ? a2 : a3;
            vshort8& bcur = (pp == 0) ? b0 : (pp == 1) ? b1
                          : (pp == 2) ? b2 : b3;
            vshort8 af;
            #pragma unroll
            for (int e = 0; e < 8; ++e) af[e] = (short)f2bf(acur[e]);
            acc = __builtin_amdgcn_mfma_f32_16x16x32_bf16(af, bcur, acc, 0, 0, 0);
        }
    }

    float* P = part + (size_t)splt * ((size_t)Nn * Cc);
    #pragma unroll
    for (int j = 0; j < 4; ++j)
        P[(size_t)(r0 + kh * 4 + j) * Cc + ll15] = acc[j];
}

// ---- K5: reduce j-split partials (8) ----
__global__ __launch_bounds__(256) void k_reduce(const float* __restrict__ part,
                                                float* __restrict__ out) {
    int i = blockIdx.x * 256 + threadIdx.x;
    float s = 0.f;
    #pragma unroll
    for (int j = 0; j < 8; ++j) s += part[(size_t)j * (Nn * Cc) + i];
    out[i] = s;
}

extern "C" void kernel_launch(void* const* d_in, const int* in_sizes, int n_in,
                              void* d_out, int out_size, void* d_ws, size_t ws_size,
                              hipStream_t stream) {
    const float* X  = (const float*)d_in[0];
    const float* A  = (const float*)d_in[1];
    const float* W  = (const float*)d_in[2];
    const float* Wl = (const float*)d_in[3];
    const float* Pk = (const float*)d_in[4];
    float* out = (float*)d_out;
    float* ws = (float*)d_ws;
    if (ws_size < (size_t)WS_FLOATS * sizeof(float)) return;

    unsigned short* Pp  = (unsigned short*)ws;      // 4 bf16 partials (16MB)
    float* part = ws;                               // gemm2 f32 partials (4MB, later)
    unsigned short* Bp  = (unsigned short*)(ws + OFF_BP);
    unsigned short* g1b = (unsigned short*)(ws + OFF_G1B);
    float* denp = ws + OFF_DEN;
    float* rsp  = ws + OFF_RS;
    float* kc   = ws + OFF_KC;
    unsigned short* Lbp = (unsigned short*)(ws + OFF_LB);

    k_front<<<272, 256, 0, stream>>>(X, W, Wl, Pk, Bp, g1b, kc);
    k_gemm1_mfma<<<512, 256, 0, stream>>>(A, Bp, g1b, Pp, denp, rsp);
    k_rowfix<<<Nn, 256, 0, stream>>>(Pp, denp, rsp, Pk, Wl, kc, Lbp);
    k_gemm2_mfma<<<1024, 256, 0, stream>>>(A, Lbp, part);
    k_reduce<<<512, 256, 0, stream>>>(part, out);
}

// Round 18
// 201.560 us; speedup vs baseline: 1.4027x; 1.0138x over previous
//
#include <hip/hip_runtime.h>
#include <math.h>

#define Nn 8192
#define Dd 256
#define Cc 16

// ---- workspace layout (floats) ----
#define OFF_BP   4194304u    // bf16 packed B fragments (4 MB)
#define OFF_G1B  5373952u    // bf16[8192] (gamma-1)
#define OFF_DEN  5378048u    // 4*8192 f32
#define OFF_RS   5410816u    // 4*8192 f32
#define OFF_KC   5443584u    // 64
#define OFF_LB   5443648u    // bf16 packed logits fragments (256 KB)
#define WS_FLOATS 5509184u

typedef short vshort8 __attribute__((ext_vector_type(8)));
typedef float vfloat4 __attribute__((ext_vector_type(4)));

#define AS1 __attribute__((address_space(1)))
#define AS3 __attribute__((address_space(3)))

__device__ __forceinline__ float clip1(float x) {
    return fminf(fmaxf(x, -1.0f + 1e-7f), 1.0f - 1e-7f);
}

__device__ __forceinline__ unsigned short f2bf(float f) {
    unsigned int u = __float_as_uint(f);
    u += 0x7fff + ((u >> 16) & 1);          // round-to-nearest-even
    return (unsigned short)(u >> 16);
}

__device__ __forceinline__ float bf2f(unsigned short b) {
    return __uint_as_float(((unsigned int)b) << 16);
}

__device__ __forceinline__ float waveReduce(float v) {
    #pragma unroll
    for (int off = 32; off; off >>= 1) v += __shfl_down(v, off);
    return v;
}

__device__ __forceinline__ float blockReduceBcast(float v, float* red) {
    int t = threadIdx.x, w = t >> 6, l = t & 63;
    v = waveReduce(v);
    if (l == 0) red[w] = v;
    __syncthreads();
    if (t == 0) red[0] = red[0] + red[1] + red[2] + red[3];
    __syncthreads();
    float r = red[0];
    __syncthreads();
    return r;
}

// ---- K1: fused X@W^T (bf16 MFMA) + mobius rescale + gamma -> packed B ----
// Blocks 0..255: front work. Blocks 256..271: per-prototype constants.
__global__ __launch_bounds__(256) void k_front(const float* __restrict__ X,
                                               const float* __restrict__ W,
                                               const float* __restrict__ Wl,
                                               const float* __restrict__ Pk,
                                               unsigned short* __restrict__ Bp,
                                               unsigned short* __restrict__ g1b,
                                               float* __restrict__ kc) {
    __shared__ __align__(16) unsigned short Xs[32][256];
    __shared__ __align__(16) unsigned short Gs[32][258];
    __shared__ float xs2[32];
    __shared__ float scal[32];
    __shared__ float red4[32][4];

    const int t = threadIdx.x;

    if (blockIdx.x >= 256) {                 // ---- consts role ----
        int k = blockIdx.x - 256;
        float* red = &red4[0][0];
        float pv = Pk[k * Dd + t];
        float wv = Wl[t * Cc + k];
        float p2 = blockReduceBcast(pv * pv, red);
        float pw = blockReduceBcast(pv * wv, red);
        float w2 = blockReduceBcast(wv * wv, red);
        if (t == 0) {
            float an  = fmaxf(sqrtf(w2), 1e-15f);
            float lam = 2.0f / fmaxf(1.0f - p2, 1e-10f);
            kc[k * 4 + 0] = p2; kc[k * 4 + 1] = pw;
            kc[k * 4 + 2] = an; kc[k * 4 + 3] = lam;
        }
        return;
    }

    const int l = t & 63, w = t >> 6;
    const int ll = l & 15, kh = l >> 4;
    const int m0 = blockIdx.x * 32;
    const int ar = t >> 3, aq = t & 7;
    const int c0 = w * 64;

    float x2p = 0.f;
    #pragma unroll
    for (int tc = 0; tc < 4; ++tc) {
        const float* xp = &X[(size_t)(m0 + ar) * Dd + tc * 64 + aq * 8];
        vfloat4 v0 = *(const vfloat4*)xp;
        vfloat4 v1 = *(const vfloat4*)(xp + 4);
        vshort8 o;
        #pragma unroll
        for (int e = 0; e < 4; ++e) {
            x2p += v0[e] * v0[e] + v1[e] * v1[e];
            o[e] = (short)f2bf(v0[e]);
            o[e + 4] = (short)f2bf(v1[e]);
        }
        int byte = (tc * 64 + aq * 8) * 2;
        *(vshort8*)((char*)&Xs[ar][0] + (byte ^ ((ar & 7) << 4))) = o;
    }
    x2p += __shfl_xor(x2p, 1); x2p += __shfl_xor(x2p, 2); x2p += __shfl_xor(x2p, 4);
    if (aq == 0) xs2[ar] = x2p;
    __syncthreads();

    vfloat4 acc[2][4];
    #pragma unroll
    for (int mi = 0; mi < 2; ++mi)
        #pragma unroll
        for (int ni = 0; ni < 4; ++ni)
            acc[mi][ni] = (vfloat4){0.f, 0.f, 0.f, 0.f};
    #pragma unroll
    for (int tc = 0; tc < 4; ++tc) {
        vshort8 bf[8];
        #pragma unroll
        for (int ni = 0; ni < 4; ++ni)
            #pragma unroll
            for (int kk = 0; kk < 2; ++kk) {
                const float* wp = &W[(size_t)(c0 + ni * 16 + ll) * Dd
                                     + tc * 64 + kh * 8 + kk * 32];
                vfloat4 b0 = *(const vfloat4*)wp;
                vfloat4 b1 = *(const vfloat4*)(wp + 4);
                vshort8 o;
                #pragma unroll
                for (int e = 0; e < 4; ++e) {
                    o[e] = (short)f2bf(b0[e]);
                    o[e + 4] = (short)f2bf(b1[e]);
                }
                bf[ni * 2 + kk] = o;
            }
        #pragma unroll
        for (int kk = 0; kk < 2; ++kk) {
            int byte = (tc * 64 + kh * 8 + kk * 32) * 2;
            vshort8 af[2];
            #pragma unroll
            for (int mi = 0; mi < 2; ++mi) {
                int row = mi * 16 + ll;
                af[mi] = *(const vshort8*)((const char*)&Xs[row][0]
                                           + (byte ^ ((row & 7) << 4)));
            }
            #pragma unroll
            for (int mi = 0; mi < 2; ++mi)
                #pragma unroll
                for (int ni = 0; ni < 4; ++ni)
                    acc[mi][ni] = __builtin_amdgcn_mfma_f32_16x16x32_bf16(
                        af[mi], bf[ni * 2 + kk], acc[mi][ni], 0, 0, 0);
        }
    }

    #pragma unroll
    for (int mi = 0; mi < 2; ++mi)
        #pragma unroll
        for (int j = 0; j < 4; ++j) {
            float p = 0.f;
            #pragma unroll
            for (int ni = 0; ni < 4; ++ni)
                p += acc[mi][ni][j] * acc[mi][ni][j];
            p += __shfl_xor(p, 1); p += __shfl_xor(p, 2);
            p += __shfl_xor(p, 4); p += __shfl_xor(p, 8);
            if (ll == 0) red4[mi * 16 + kh * 4 + j][w] = p;
        }
    __syncthreads();

    if (t < 32) {
        float mx2 = red4[t][0] + red4[t][1] + red4[t][2] + red4[t][3];
        float xn = fmaxf(sqrtf(xs2[t]), 1e-15f);
        float mxn = fmaxf(sqrtf(mx2), 1e-15f);
        float s = tanhf(mxn / xn * atanhf(clip1(xn))) / mxn;
        float xw2 = s * s * mx2;
        float gamma = 2.0f / fmaxf(1.0f - xw2, 1e-10f);
        scal[t] = gamma * s;
        g1b[m0 + t] = f2bf(gamma - 1.0f);
    }
    __syncthreads();

    #pragma unroll
    for (int mi = 0; mi < 2; ++mi)
        #pragma unroll
        for (int ni = 0; ni < 4; ++ni) {
            int row = mi * 16 + kh * 4;
            int col = c0 + ni * 16 + ll;
            #pragma unroll
            for (int j = 0; j < 4; ++j)
                Gs[row + j][col] = f2bf(scal[row + j] * acc[mi][ni][j]);
        }
    __syncthreads();

    const int s = blockIdx.x;
    #pragma unroll
    for (int pass = 0; pass < 4; ++pass) {
        int c = pass * 256 + t;
        int gni = c >> 6, lc = c & 63;
        int col = (gni >> 2) * 64 + (gni & 3) * 16 + (lc & 15);
        int kh8 = (lc >> 4) * 8;
        vshort8 o;
        #pragma unroll
        for (int e = 0; e < 8; ++e) o[e] = (short)Gs[kh8 + e][col];
        *(vshort8*)&Bp[((size_t)(s * 16 + gni) * 64 + lc) * 8] = o;
    }
}

// ======== K2 helpers ========
__device__ __forceinline__ void g2_issueB(const unsigned short* __restrict__ Bp,
        unsigned short (&BsB)[16][512], int splt, int slab, int w, int l) {
    #pragma unroll
    for (int ni = 0; ni < 4; ++ni)
        __builtin_amdgcn_global_load_lds(
            (const AS1 unsigned int*)
                (Bp + ((size_t)((splt * 64 + slab) * 16 + w * 4 + ni) * 512) + l * 8),
            (AS3 unsigned int*)&BsB[w * 4 + ni][0], 16, 0, 0);
}

__device__ __forceinline__ void g2_loadA(const float* __restrict__ Abase,
                                         int tile, float (&a8)[8]) {
    const vfloat4* p = (const vfloat4*)(Abase + tile * 32);
    *(vfloat4*)&a8[0] = p[0];
    *(vfloat4*)&a8[4] = p[1];
}

__device__ __forceinline__ void g2_stage(unsigned short (&AsT)[2048],
        const unsigned short* g1s, const float (&a8)[8],
        int tile, int rowst, int kq, float& dacc, float& racc) {
    vshort8 gv = *(const vshort8*)&g1s[tile * 32 + kq * 8];
    vshort8 o;
    #pragma unroll
    for (int e = 0; e < 8; ++e) {
        float av = a8[e];
        o[e] = (short)f2bf(av);
        dacc += av * bf2f((unsigned short)gv[e]);
        racc += av;
    }
    *(vshort8*)((char*)&AsT[0] + rowst * 64 + ((kq * 16) ^ ((rowst & 3) << 4))) = o;
}

__device__ __forceinline__ void g2_mfma(const unsigned short (&AsT)[2048],
        const unsigned short (&BsB)[16][512], int w, int kh, int ll15, int l,
        vfloat4 (&acc)[4][4]) {
    vshort8 bf[4], af[4];
    #pragma unroll
    for (int ni = 0; ni < 4; ++ni)
        bf[ni] = *(const vshort8*)&BsB[w * 4 + ni][l * 8];
    #pragma unroll
    for (int mi = 0; mi < 4; ++mi) {
        int row = mi * 16 + ll15;
        af[mi] = *(const vshort8*)((const char*)&AsT[0]
                  + row * 64 + ((kh * 16) ^ ((row & 3) << 4)));
    }
    __builtin_amdgcn_s_setprio(1);
    #pragma unroll
    for (int mi = 0; mi < 4; ++mi)
        #pragma unroll
        for (int ni = 0; ni < 4; ++ni)
            acc[mi][ni] = __builtin_amdgcn_mfma_f32_16x16x32_bf16(
                af[mi], bf[ni], acc[mi][ni], 0, 0, 0);
    __builtin_amdgcn_s_setprio(0);
}

// ---- K2: bf16 partials[split] = A(k-slice) @ G ----
// SUPERPHASE schedule: Bs is wave-private (no barrier needed); the barrier
// exists only to publish shared A. Stage A in groups of 4 k-tiles
// (As[2][4][2048] dbuf) -> ONE barrier per 4 phases (16 total, was 64).
// Phase q: issue B(q+1) [2-deep ring]; load A tile q+5; vmcnt(6) retires
// [B(q), a(q+4)]; stage tile q+4 into As[(sp+1)&1][q&3]; MFMA.
__global__ __launch_bounds__(256, 2) void k_gemm1_mfma(
        const float* __restrict__ A,
        const unsigned short* __restrict__ Bp,
        const unsigned short* __restrict__ g1b,
        unsigned short* __restrict__ Pp,
        float* __restrict__ denp,
        float* __restrict__ rsp) {
    __shared__ __align__(16) unsigned short As[2][4][2048];  // 32 KB
    __shared__ __align__(16) unsigned short Bs[2][16][512];  // 32 KB
    __shared__ __align__(16) unsigned short g1s[2048];       // 4 KB

    const int t = threadIdx.x, l = t & 63, w = t >> 6;
    const int id = blockIdx.x;
    const int splt = id & 3;
    const int m0 = (id >> 2) * 64;
    const int kb = splt * 2048;
    const int kh = l >> 4, ll15 = l & 15;
    const int rowst = t >> 2, kq = t & 3;

    const float* Abase = &A[(size_t)(m0 + rowst) * Nn + kb + kq * 8];

    vfloat4 acc[4][4];
    #pragma unroll
    for (int mi = 0; mi < 4; ++mi)
        #pragma unroll
        for (int ni = 0; ni < 4; ++ni)
            acc[mi][ni] = (vfloat4){0.f, 0.f, 0.f, 0.f};
    float dacc = 0.f, racc = 0.f;
    float ar0[8], ar1[8];                    // A reg ring (parity = phase)

    // ---- prologue: g1, B(0), tiles 0-3 staged, tile 4 primed ----
    {
        uint4 g1v = *(const uint4*)&g1b[kb + t * 8];
        g2_issueB(Bp, Bs[0], splt, 0, w, l);
        float p0[8], p1[8], p2[8], p3[8];
        g2_loadA(Abase, 0, p0);
        g2_loadA(Abase, 1, p1);
        g2_loadA(Abase, 2, p2);
        g2_loadA(Abase, 3, p3);
        g2_loadA(Abase, 4, ar1);             // primes ring for q=0 stage
        asm volatile("s_waitcnt vmcnt(0)" ::: "memory");
        *(uint4*)&g1s[t * 8] = g1v;
        g2_stage(As[0][0], g1s, p0, 0, rowst, kq, dacc, racc);
        g2_stage(As[0][1], g1s, p1, 1, rowst, kq, dacc, racc);
        g2_stage(As[0][2], g1s, p2, 2, rowst, kq, dacc, racc);
        g2_stage(As[0][3], g1s, p3, 3, rowst, kq, dacc, racc);
        asm volatile("s_waitcnt lgkmcnt(0)" ::: "memory");
        __builtin_amdgcn_s_barrier();
        __builtin_amdgcn_sched_barrier(0);
    }

    // ---- superphases 0..13, unrolled x2 for literal buffer parity ----
    #pragma unroll 1
    for (int v = 0; v < 7; ++v) {
        #pragma unroll
        for (int h = 0; h < 2; ++h) {
            const int sp = v * 2 + h;        // h = sp&1 (literal)
            #pragma unroll
            for (int pp = 0; pp < 4; ++pp) {
                const int q = sp * 4 + pp;
                g2_issueB(Bp, Bs[(pp + 1) & 1], splt, q + 1, w, l);
                if (pp & 1) g2_loadA(Abase, q + 5, ar1);
                else        g2_loadA(Abase, q + 5, ar0);
                asm volatile("s_waitcnt vmcnt(6)" ::: "memory");
                if (pp & 1) g2_stage(As[h ^ 1][pp], g1s, ar0, q + 4, rowst, kq, dacc, racc);
                else        g2_stage(As[h ^ 1][pp], g1s, ar1, q + 4, rowst, kq, dacc, racc);
                g2_mfma(As[h][pp], Bs[pp & 1], w, kh, ll15, l, acc);
                if (pp == 3) {
                    asm volatile("s_waitcnt lgkmcnt(0)" ::: "memory");
                    __builtin_amdgcn_s_barrier();
                    __builtin_amdgcn_sched_barrier(0);
                }
            }
        }
    }

    // ---- superphase 14 (reads As[0], writes As[1]); q = 56..59 ----
    #pragma unroll
    for (int pp = 0; pp < 3; ++pp) {         // q = 56,57,58 (loads t61..t63)
        const int q = 56 + pp;
        g2_issueB(Bp, Bs[(pp + 1) & 1], splt, q + 1, w, l);
        if (pp & 1) g2_loadA(Abase, q + 5, ar1);
        else        g2_loadA(Abase, q + 5, ar0);
        asm volatile("s_waitcnt vmcnt(6)" ::: "memory");
        if (pp & 1) g2_stage(As[1][pp], g1s, ar0, q + 4, rowst, kq, dacc, racc);
        else        g2_stage(As[1][pp], g1s, ar1, q + 4, rowst, kq, dacc, racc);
        g2_mfma(As[0][pp], Bs[pp & 1], w, kh, ll15, l, acc);
    }
    {   // q = 59: no load; vmcnt(4) retires [B59, t63]; stage t63 slot3
        g2_issueB(Bp, Bs[0], splt, 60, w, l);
        asm volatile("s_waitcnt vmcnt(4)" ::: "memory");
        g2_stage(As[1][3], g1s, ar0, 63, rowst, kq, dacc, racc);
        g2_mfma(As[0][3], Bs[1], w, kh, ll15, l, acc);
        asm volatile("s_waitcnt lgkmcnt(0)" ::: "memory");
        __builtin_amdgcn_s_barrier();
        __builtin_amdgcn_sched_barrier(0);
    }
    // ---- superphase 15 (reads As[1]); q = 60..63; no stages, no barriers ----
    g2_issueB(Bp, Bs[1], splt, 61, w, l);
    asm volatile("s_waitcnt vmcnt(4)" ::: "memory");
    g2_mfma(As[1][0], Bs[0], w, kh, ll15, l, acc);
    g2_issueB(Bp, Bs[0], splt, 62, w, l);
    asm volatile("s_waitcnt vmcnt(4)" ::: "memory");
    g2_mfma(As[1][1], Bs[1], w, kh, ll15, l, acc);
    g2_issueB(Bp, Bs[1], splt, 63, w, l);
    asm volatile("s_waitcnt vmcnt(4)" ::: "memory");
    g2_mfma(As[1][2], Bs[0], w, kh, ll15, l, acc);
    asm volatile("s_waitcnt vmcnt(0)" ::: "memory");
    g2_mfma(As[1][3], Bs[1], w, kh, ll15, l, acc);

    // ---- den/rs ----
    dacc += __shfl_xor(dacc, 1); dacc += __shfl_xor(dacc, 2);
    racc += __shfl_xor(racc, 1); racc += __shfl_xor(racc, 2);
    if (kq == 0) {
        denp[splt * Nn + m0 + rowst] = dacc;
        rsp [splt * Nn + m0 + rowst] = racc;
    }

    // ---- store bf16 partial ----
    unsigned short* P = Pp + (size_t)splt * ((size_t)Nn * Dd);
    #pragma unroll
    for (int mi = 0; mi < 4; ++mi)
        #pragma unroll
        for (int ni = 0; ni < 4; ++ni) {
            int row = m0 + mi * 16 + (kh << 2);
            int col = w * 64 + ni * 16 + ll15;
            #pragma unroll
            for (int j = 0; j < 4; ++j)
                P[(size_t)(row + j) * Dd + col] = f2bf(acc[mi][ni][j]);
        }
}

// ---- K3: per-row gyromidpoint chain + H1 + hyperbolic logits ----
// Writes logits DIRECTLY in packed MFMA B-fragment order.
__global__ __launch_bounds__(256) void k_rowfix(const unsigned short* __restrict__ Pp,
                                                const float* __restrict__ denp,
                                                const float* __restrict__ rsp,
                                                const float* __restrict__ Pk,
                                                const float* __restrict__ Wl,
                                                const float* __restrict__ kc,
                                                unsigned short* __restrict__ Lb) {
    __shared__ float red[8];
    __shared__ float hs[256];
    __shared__ float PQ[16][2];
    int i = blockIdx.x, t = threadIdx.x;
    float nom = 0.f;
    #pragma unroll
    for (int s = 0; s < 4; ++s)
        nom += bf2f(Pp[(size_t)s * Nn * Dd + (size_t)i * Dd + t]);
    float dv = denp[i] + denp[Nn + i] + denp[2 * Nn + i] + denp[3 * Nn + i];
    dv = (fabsf(dv) < 1e-10f) ? 1e-10f : dv;
    float tm = nom / dv;
    float r2 = blockReduceBcast(tm * tm, red);
    float r = fmaxf(sqrtf(r2), 1e-15f);
    float mmul = tanhf(0.5f * atanhf(clip1(r))) / r;
    float mj = mmul * tm;
    float mn2 = blockReduceBcast(mj * mj, red);
    float mn = fmaxf(sqrtf(mn2), 1e-15f);
    float sA = rsp[i] + rsp[Nn + i] + rsp[2 * Nn + i] + rsp[3 * Nn + i];
    float axmul = tanhf(sA * atanhf(clip1(mn))) / mn;
    float axw = axmul * mj;
    float yn2 = blockReduceBcast(axw * axw, red);
    float yn = fmaxf(sqrtf(yn2), 1e-15f);
    float v = atanhf(clip1(yn)) / yn * axw;
    float u = fmaxf(v, 0.0f);
    float un2 = blockReduceBcast(u * u, red);
    float un = fmaxf(sqrtf(un2), 1e-15f);
    float h = tanhf(un) / un * u;
    float h2 = blockReduceBcast(h * h, red);
    hs[t] = h;
    __syncthreads();
    int w = t >> 6, l = t & 63;
    #pragma unroll
    for (int kk = 0; kk < 4; ++kk) {
        int k = w * 4 + kk;
        float pp = 0.f, qq = 0.f;
        #pragma unroll
        for (int m = 0; m < 4; ++m) {
            float hv = hs[l + 64 * m];
            pp += hv * Pk[k * Dd + l + 64 * m];
            qq += hv * Wl[(l + 64 * m) * Cc + k];
        }
        pp = waveReduce(pp);
        qq = waveReduce(qq);
        if (l == 0) { PQ[k][0] = pp; PQ[k][1] = qq; }
    }
    __syncthreads();
    if (t < 16) {
        int k = t;
        float p2 = kc[k * 4 + 0], pw = kc[k * 4 + 1];
        float an = kc[k * 4 + 2], lam = kc[k * 4 + 3];
        float P = PQ[k][0], Q = PQ[k][1];
        float alpha = 1.0f - 2.0f * P + h2;
        float beta  = 1.0f - p2;
        float Dm = fmaxf(1.0f - 2.0f * P + p2 * h2, 1e-15f);
        float za  = (-alpha * pw + beta * Q) / Dm;
        float zn2 = (alpha * alpha * p2 - 2.0f * alpha * beta * P + beta * beta * h2)
                    / (Dm * Dm);
        float dd = fmaxf(1.0f - zn2, 1e-10f) * an;
        float dist = asinhf(2.0f * za / dd);
        float lgv = lam * an * dist;
        int kt = i >> 5, r = i & 31;
        Lb[(size_t)kt * 512 + (size_t)(((r >> 3) * 16 + k) * 8) + (r & 7)]
            = f2bf(lgv);
    }
}

// ---- K4: out partials = A @ L via MFMA; no LDS, no barriers ----
__global__ __launch_bounds__(256, 4) void k_gemm2_mfma(
        const float* __restrict__ A,
        const unsigned short* __restrict__ Lb,
        float* __restrict__ part) {
    const int t = threadIdx.x, l = t & 63, w = t >> 6;
    const int id = blockIdx.x;
    const int splt = id & 7;
    const int m0 = (id >> 3) * 64;
    const int kb = splt * 1024;
    const int kh = l >> 4, ll15 = l & 15;
    const int r0 = m0 + w * 16;

    const float* Ab = &A[(size_t)(r0 + ll15) * Nn + kb + kh * 8];
    const unsigned short* Lbb = &Lb[(size_t)(splt * 32) * 512 + l * 8];

    vfloat4 acc = (vfloat4){0.f, 0.f, 0.f, 0.f};
    float a0[8], a1[8], a2[8], a3[8];
    vshort8 b0, b1, b2, b3;

    *(vfloat4*)&a0[0] = *(const vfloat4*)(Ab);
    *(vfloat4*)&a0[4] = *(const vfloat4*)(Ab + 4);
    b0 = *(const vshort8*)(Lbb);
    *(vfloat4*)&a1[0] = *(const vfloat4*)(Ab + 32);
    *(vfloat4*)&a1[4] = *(const vfloat4*)(Ab + 36);
    b1 = *(const vshort8*)(Lbb + 512);
    *(vfloat4*)&a2[0] = *(const vfloat4*)(Ab + 64);
    *(vfloat4*)&a2[4] = *(const vfloat4*)(Ab + 68);
    b2 = *(const vshort8*)(Lbb + 1024);

    for (int u = 0; u < 8; ++u) {
        #pragma unroll
        for (int pp = 0; pp < 4; ++pp) {
            const int kt = u * 4 + pp;
            if (kt < 29) {
                float (&adst)[8] = (pp == 0) ? a3 : (pp == 1) ? a0
                                 : (pp == 2) ? a1 : a2;
                vshort8& bdst = (pp == 0) ? b3 : (pp == 1) ? b0
                              : (pp == 2) ? b1 : b2;
                *(vfloat4*)&adst[0] = *(const vfloat4*)(Ab + (kt + 3) * 32);
                *(vfloat4*)&adst[4] = *(const vfloat4*)(Ab + (kt + 3) * 32 + 4);
                bdst = *(const vshort8*)(Lbb + (kt + 3) * 512);
            }
            float (&acur)[8] = (pp == 0) ? a0 : (pp == 1) ? a1
                             : (pp == 2) ? a2 : a3;
            vshort8& bcur = (pp == 0) ? b0 : (pp == 1) ? b1
                          : (pp == 2) ? b2 : b3;
            vshort8 af;
            #pragma unroll
            for (int e = 0; e < 8; ++e) af[e] = (short)f2bf(acur[e]);
            acc = __builtin_amdgcn_mfma_f32_16x16x32_bf16(af, bcur, acc, 0, 0, 0);
        }
    }

    float* P = part + (size_t)splt * ((size_t)Nn * Cc);
    #pragma unroll
    for (int j = 0; j < 4; ++j)
        P[(size_t)(r0 + kh * 4 + j) * Cc + ll15] = acc[j];
}

// ---- K5: reduce j-split partials (8) ----
__global__ __launch_bounds__(256) void k_reduce(const float* __restrict__ part,
                                                float* __restrict__ out) {
    int i = blockIdx.x * 256 + threadIdx.x;
    float s = 0.f;
    #pragma unroll
    for (int j = 0; j < 8; ++j) s += part[(size_t)j * (Nn * Cc) + i];
    out[i] = s;
}

extern "C" void kernel_launch(void* const* d_in, const int* in_sizes, int n_in,
                              void* d_out, int out_size, void* d_ws, size_t ws_size,
                              hipStream_t stream) {
    const float* X  = (const float*)d_in[0];
    const float* A  = (const float*)d_in[1];
    const float* W  = (const float*)d_in[2];
    const float* Wl = (const float*)d_in[3];
    const float* Pk = (const float*)d_in[4];
    float* out = (float*)d_out;
    float* ws = (float*)d_ws;
    if (ws_size < (size_t)WS_FLOATS * sizeof(float)) return;

    unsigned short* Pp  = (unsigned short*)ws;      // 4 bf16 partials (16MB)
    float* part = ws;                               // gemm2 f32 partials (4MB, later)
    unsigned short* Bp  = (unsigned short*)(ws + OFF_BP);
    unsigned short* g1b = (unsigned short*)(ws + OFF_G1B);
    float* denp = ws + OFF_DEN;
    float* rsp  = ws + OFF_RS;
    float* kc   = ws + OFF_KC;
    unsigned short* Lbp = (unsigned short*)(ws + OFF_LB);

    k_front<<<272, 256, 0, stream>>>(X, W, Wl, Pk, Bp, g1b, kc);
    k_gemm1_mfma<<<512, 256, 0, stream>>>(A, Bp, g1b, Pp, denp, rsp);
    k_rowfix<<<Nn, 256, 0, stream>>>(Pp, denp, rsp, Pk, Wl, kc, Lbp);
    k_gemm2_mfma<<<1024, 256, 0, stream>>>(A, Lbp, part);
    k_reduce<<<512, 256, 0, stream>>>(part, out);
}